// Round 3
// baseline (1735.831 us; speedup 1.0000x reference)
//
#include <hip/hip_runtime.h>
#include <math.h>

#define N_NODES 50000
#define N_PAD   50048            // padded rows for 128-row GEMM tiles
#define E_EDGES 1600000
#define ETOT    (E_EDGES + N_NODES)
#define EPAD    (E_EDGES + 8 * N_NODES)   // CSR rows padded to multiple of 8
#define IN_DIM  300
#define KP1     320              // IN_DIM padded to mult of 32
#define HID     256
#define HEADS   8
#define OC      32
#define LAYERS  4
#define BSAMP   1024
#define NEG_SLOPE 0.2f

// XCD-bucketed CSR build
#define NB     8                 // buckets = XCDs (also heads in agg)
#define NPB    6250              // nodes per bucket (50000/8)
#define BCAP   262144            // per-bucket partition capacity (mean 206k)
#define NBLK_P 512               // partition blocks
#define NBLK_S 196               // scan blocks (50000/256 rounded up)
#define NBLK_B 2048              // bucket count/fill blocks (256 per bucket)

// agg: wave = 32 (node,head) x 2 channel-half lanes; 1 node-group per wave
#define NGRP   ((N_NODES + 31) / 32)      // 1563 groups of 32 nodes
#define NAGG   3128                       // 391 blocks/head * 8 heads
#define WPH    ((NAGG / NB) * 4)          // 1564 waves per head

typedef unsigned long long ull;
typedef unsigned short u16;
typedef _Float16 half8 __attribute__((ext_vector_type(8)));
typedef float f32x4 __attribute__((ext_vector_type(4)));

#define GLDS16(g, l) __builtin_amdgcn_global_load_lds( \
    (const __attribute__((address_space(1))) void*)(g), \
    (__attribute__((address_space(3))) void*)(l), 16, 0, 0)

// ---------------------------------------------------------------- CSR build
// Two-pass block-local radix partition by tgt bucket. No global atomics.

__global__ __launch_bounds__(256) void part_count_kernel(const int* __restrict__ tgt,
                                                         int* __restrict__ gcount) {
    __shared__ int cnt[NB];
    if (threadIdx.x < NB) cnt[threadIdx.x] = 0;
    __syncthreads();
    const int chunk = (ETOT + NBLK_P - 1) / NBLK_P;
    int beg = blockIdx.x * chunk;
    int end = min(beg + chunk, ETOT);
    for (int e = beg + threadIdx.x; e < end; e += 256) {
        int t_ = (e < E_EDGES) ? tgt[e] : (e - E_EDGES);
        atomicAdd(&cnt[t_ / NPB], 1);
    }
    __syncthreads();
    if (threadIdx.x < NB) gcount[blockIdx.x * NB + threadIdx.x] = cnt[threadIdx.x];
}

// parallel scan over NBLK_P block-counts x NB buckets (1 block, 512 threads)
__global__ __launch_bounds__(512) void part_scan_kernel(const int* __restrict__ gcount,
                                                        int* __restrict__ goff,
                                                        int* __restrict__ bcnt) {
    __shared__ int arr[NBLK_P][NB];
    int k = threadIdx.x;
    int4 a = ((const int4*)gcount)[k * 2];
    int4 b = ((const int4*)gcount)[k * 2 + 1];
    int own[NB] = {a.x, a.y, a.z, a.w, b.x, b.y, b.z, b.w};
    #pragma unroll
    for (int j = 0; j < NB; j++) arr[k][j] = own[j];
    __syncthreads();
    for (int off = 1; off < NBLK_P; off <<= 1) {
        int tmp[NB];
        #pragma unroll
        for (int j = 0; j < NB; j++) tmp[j] = (k >= off) ? arr[k - off][j] : 0;
        __syncthreads();
        #pragma unroll
        for (int j = 0; j < NB; j++) arr[k][j] += tmp[j];
        __syncthreads();
    }
    int ex[NB];
    #pragma unroll
    for (int j = 0; j < NB; j++) ex[j] = arr[k][j] - own[j];   // exclusive
    ((int4*)goff)[k * 2]     = make_int4(ex[0], ex[1], ex[2], ex[3]);
    ((int4*)goff)[k * 2 + 1] = make_int4(ex[4], ex[5], ex[6], ex[7]);
    if (k == NBLK_P - 1) {
        #pragma unroll
        for (int j = 0; j < NB; j++) bcnt[j] = arr[k][j];
    }
}

__global__ __launch_bounds__(256) void part_scatter_kernel(const int* __restrict__ src,
                                                           const int* __restrict__ tgt,
                                                           const int* __restrict__ goff,
                                                           ull* __restrict__ bpart) {
    __shared__ int cur[NB];
    if (threadIdx.x < NB) cur[threadIdx.x] = goff[blockIdx.x * NB + threadIdx.x];
    __syncthreads();
    const int chunk = (ETOT + NBLK_P - 1) / NBLK_P;
    int beg = blockIdx.x * chunk;
    int end = min(beg + chunk, ETOT);
    for (int e = beg + threadIdx.x; e < end; e += 256) {
        int s_, t_;
        if (e < E_EDGES) { s_ = src[e]; t_ = tgt[e]; }
        else             { s_ = t_ = e - E_EDGES; }
        int b = t_ / NPB;
        int pos = atomicAdd(&cur[b], 1);
        bpart[(size_t)b * BCAP + pos] = ((ull)(unsigned)t_ << 32) | (unsigned)s_;
    }
}

// per-bucket degree count (blockIdx%8 = bucket -> XCD-local counts lines)
__global__ __launch_bounds__(256) void count_edges_kernel(const ull* __restrict__ bpart,
                                                          const int* __restrict__ bcnt,
                                                          int* counts) {
    int b = blockIdx.x & (NB - 1);
    int ib = blockIdx.x >> 3;
    int nblk = gridDim.x >> 3;
    int nb = bcnt[b];
    const ull* bp = bpart + (size_t)b * BCAP;
    for (int i = ib * 256 + threadIdx.x; i < nb; i += nblk * 256)
        atomicAdd(&counts[(int)(bp[i] >> 32)], 1);
}

// ---------------- parallel scan of padded counts (3 tiny kernels) ----------
__global__ __launch_bounds__(256) void scan1_kernel(const int* __restrict__ counts,
                                                    int* __restrict__ row_ptr,
                                                    int* __restrict__ bsum) {
    __shared__ int sums[256];
    int t = threadIdx.x;
    int i = blockIdx.x * 256 + t;
    int c = (i < N_NODES) ? ((counts[i] + 7) & ~7) : 0;
    sums[t] = c;
    __syncthreads();
    for (int off = 1; off < 256; off <<= 1) {
        int a = sums[t];
        int u = (t >= off) ? sums[t - off] : 0;
        __syncthreads();
        sums[t] = a + u;
        __syncthreads();
    }
    if (i < N_NODES) row_ptr[i] = sums[t] - c;   // local exclusive
    if (t == 255) bsum[blockIdx.x] = sums[255];
}

__global__ __launch_bounds__(256) void scan2_kernel(const int* __restrict__ bsum,
                                                    int* __restrict__ boff,
                                                    int* __restrict__ row_ptr) {
    __shared__ int sums[256];
    int t = threadIdx.x;
    int b = (t < NBLK_S) ? bsum[t] : 0;
    sums[t] = b;
    __syncthreads();
    for (int off = 1; off < 256; off <<= 1) {
        int a = sums[t];
        int u = (t >= off) ? sums[t - off] : 0;
        __syncthreads();
        sums[t] = a + u;
        __syncthreads();
    }
    if (t < NBLK_S) boff[t] = sums[t] - b;
    if (t == 255) row_ptr[N_NODES] = sums[255];
}

__global__ __launch_bounds__(256) void scan3_kernel(int* __restrict__ row_ptr,
                                                    const int* __restrict__ boff,
                                                    int* __restrict__ cursor) {
    int i = blockIdx.x * 256 + threadIdx.x;
    if (i >= N_NODES) return;
    int v = row_ptr[i] + boff[blockIdx.x];
    row_ptr[i] = v;
    cursor[i]  = v;
}

// per-bucket scatter into col (cursor + col lines XCD-local); col is u16
__global__ __launch_bounds__(256) void fill_edges_kernel(const ull* __restrict__ bpart,
                                                         const int* __restrict__ bcnt,
                                                         int* cursor, u16* __restrict__ col) {
    int b = blockIdx.x & (NB - 1);
    int ib = blockIdx.x >> 3;
    int nblk = gridDim.x >> 3;
    int nb = bcnt[b];
    const ull* bp = bpart + (size_t)b * BCAP;
    for (int i = ib * 256 + threadIdx.x; i < nb; i += nblk * 256) {
        ull pk = bp[i];
        int t_ = (int)(pk >> 32);
        int s_ = (int)pk;
        int pos = atomicAdd(&cursor[t_], 1);
        col[pos] = (u16)s_;
    }
}

// ---------------- degree sort (bucket sort by true degree) -----------------
__global__ __launch_bounds__(256) void dsort_count_kernel(const int* __restrict__ counts,
                                                          int* __restrict__ degcnt) {
    int i = blockIdx.x * 256 + threadIdx.x;
    if (i >= N_NODES) return;
    int d = min(counts[i], 255);
    atomicAdd(&degcnt[d], 1);
}

__global__ __launch_bounds__(256) void dsort_scan_kernel(const int* __restrict__ degcnt,
                                                         int* __restrict__ degoff) {
    __shared__ int s[256];
    int t = threadIdx.x;
    int v = degcnt[t];
    s[t] = v;
    __syncthreads();
    for (int off = 1; off < 256; off <<= 1) {
        int a = s[t];
        int u = (t >= off) ? s[t - off] : 0;
        __syncthreads();
        s[t] = a + u;
        __syncthreads();
    }
    degoff[t] = s[t] - v;   // exclusive
}

__global__ __launch_bounds__(256) void dsort_fill_kernel(const int* __restrict__ counts,
                                                         int* degoff,
                                                         int* __restrict__ perm) {
    int i = blockIdx.x * 256 + threadIdx.x;
    if (i >= N_NODES) return;
    int d = min(counts[i], 255);
    int pos = atomicAdd(&degoff[d], 1);
    perm[pos] = i;
}

// ---------------------------------------------------------------- fp32 -> fp16 casts

__global__ __launch_bounds__(256) void cast_x_kernel(const float* __restrict__ x, _Float16* __restrict__ xh) {
    int i = blockIdx.x * 256 + threadIdx.x;          // over 50000*40 half8s
    if (i >= N_NODES * (KP1 / 8)) return;
    int r = i / (KP1 / 8), c8 = i % (KP1 / 8);
    half8 o;
    const float4* xr = (const float4*)(x + (size_t)r * IN_DIM);
    if (c8 < 37) {
        float4 u = xr[c8 * 2], v = xr[c8 * 2 + 1];
        o[0] = (_Float16)u.x; o[1] = (_Float16)u.y; o[2] = (_Float16)u.z; o[3] = (_Float16)u.w;
        o[4] = (_Float16)v.x; o[5] = (_Float16)v.y; o[6] = (_Float16)v.z; o[7] = (_Float16)v.w;
    } else if (c8 == 37) {
        float4 u = xr[74];
        o[0] = (_Float16)u.x; o[1] = (_Float16)u.y; o[2] = (_Float16)u.z; o[3] = (_Float16)u.w;
        o[4] = o[5] = o[6] = o[7] = (_Float16)0.f;
    } else {
        #pragma unroll
        for (int j = 0; j < 8; j++) o[j] = (_Float16)0.f;
    }
    ((half8*)xh)[i] = o;
}

__global__ __launch_bounds__(256) void cast_w1_kernel(const float* __restrict__ W, _Float16* __restrict__ Wt) {
    int i = blockIdx.x * 256 + threadIdx.x;
    if (i >= HID * KP1) return;
    int n = i / KP1, k = i % KP1;
    float v = (k < IN_DIM) ? W[(size_t)k * HID + n] : 0.f;
    Wt[i] = (_Float16)v;
}

__global__ __launch_bounds__(256) void cast_wc_kernel(const float* __restrict__ W, _Float16* __restrict__ Wt) {
    int i = blockIdx.x * 256 + threadIdx.x;
    if (i >= LAYERS * HID * HID) return;
    int l = i / (HID * HID);
    int r = i % (HID * HID);
    int n = r / HID, k = r % HID;
    Wt[i] = (_Float16)W[(size_t)l * HID * HID + (size_t)k * HID + n];
}

// ---------------------------------------------------------------- fp16 MFMA GEMM
// headmajor=1 writes C as [head][node][32] (stride N_NODES rows per head slice)
__global__ __launch_bounds__(256) void gemm_mfma_kernel(const _Float16* __restrict__ A,
                                                        const _Float16* __restrict__ Wt,
                                                        const float* __restrict__ bias,
                                                        _Float16* __restrict__ C,
                                                        int M, int Kp, int addbias,
                                                        int headmajor) {
    __shared__ _Float16 As[128][32];
    __shared__ _Float16 Bs[128][32];
    const int tid = threadIdx.x;
    const int m0 = blockIdx.x * 128;
    const int n0 = blockIdx.y * 128;
    const int w = tid >> 6, lane = tid & 63;
    const int wm = (w & 1) * 64, wn = (w >> 1) * 64;
    const int quad = lane >> 4, m16 = lane & 15;

    f32x4 acc[4][4];
    #pragma unroll
    for (int i = 0; i < 4; i++)
        #pragma unroll
        for (int j = 0; j < 4; j++)
            acc[i][j] = (f32x4){0.f, 0.f, 0.f, 0.f};

    char* lA = (char*)&As[0][0] + w * 1024;   // wave-uniform LDS bases
    char* lB = (char*)&Bs[0][0] + w * 1024;

    for (int k0 = 0; k0 < Kp; k0 += 32) {
        #pragma unroll
        for (int i = 0; i < 2; i++) {
            int seg = tid + i * 256;
            int row = seg >> 2, off = seg & 3;
            GLDS16(&A[(size_t)(m0 + row) * Kp + k0 + off * 8], lA + i * 4096);
            GLDS16(&Wt[(size_t)(n0 + row) * Kp + k0 + off * 8], lB + i * 4096);
        }
        __syncthreads();

        half8 af[4], bf[4];
        #pragma unroll
        for (int i = 0; i < 4; i++) {
            af[i] = *(const half8*)&As[wm + i * 16 + m16][quad * 8];
            bf[i] = *(const half8*)&Bs[wn + i * 16 + m16][quad * 8];
        }
        #pragma unroll
        for (int mi = 0; mi < 4; mi++)
            #pragma unroll
            for (int ni = 0; ni < 4; ni++)
                acc[mi][ni] = __builtin_amdgcn_mfma_f32_16x16x32_f16(af[mi], bf[ni], acc[mi][ni], 0, 0, 0);
        __syncthreads();
    }

    #pragma unroll
    for (int mi = 0; mi < 4; mi++) {
        #pragma unroll
        for (int r = 0; r < 4; r++) {
            int row = m0 + wm + mi * 16 + quad * 4 + r;
            if (row < M) {
                #pragma unroll
                for (int ni = 0; ni < 4; ni++) {
                    int colg = n0 + wn + ni * 16 + m16;
                    float v = acc[mi][ni][r];
                    if (addbias) v += bias[colg];
                    if (headmajor) {
                        int hd = colg >> 5, oc = colg & 31;
                        C[((size_t)hd * N_NODES + row) * 32 + oc] = (_Float16)v;
                    } else {
                        C[(size_t)row * HID + colg] = (_Float16)v;
                    }
                }
            }
        }
    }
}

// ---------------------------------------------------------------- attention scores
// hw is head-major [head][node][32]; s arrays head-major [head][node].
// Wave = 8 nodes; lane = (node nd=lane>>3, head hd=lane&7).
__global__ __launch_bounds__(256) void score_kernel(const _Float16* __restrict__ hw,
                                                    const float* __restrict__ att_dst,
                                                    const float* __restrict__ att_src,
                                                    float* __restrict__ s_dst,
                                                    float* __restrict__ s_src) {
    int wv = threadIdx.x >> 6, lane = threadIdx.x & 63;
    int nd = lane >> 3, hd = lane & 7;
    float4 ad[8], as4[8];
    const float4* A4d = (const float4*)att_dst;
    const float4* A4s = (const float4*)att_src;
    #pragma unroll
    for (int j = 0; j < 8; j++) { ad[j] = A4d[hd * 8 + j]; as4[j] = A4s[hd * 8 + j]; }
    const half8* hw8 = (const half8*)hw;
    int nwaves = gridDim.x * 4;
    for (int g = blockIdx.x * 4 + wv; g < N_NODES / 8; g += nwaves) {
        int node = g * 8 + nd;
        float sd = 0.f, ss = 0.f;
        #pragma unroll
        for (int k = 0; k < 4; k++) {
            half8 v = hw8[((size_t)hd * N_NODES + node) * 4 + k];
            #pragma unroll
            for (int i = 0; i < 8; i++) {
                float f = (float)v[i];
                int q = k * 8 + i;
                sd += f * ((const float*)&ad[q >> 2])[q & 3];
                ss += f * ((const float*)&as4[q >> 2])[q & 3];
            }
        }
        s_dst[(size_t)hd * N_NODES + node] = sd;
        s_src[(size_t)hd * N_NODES + node] = ss;
    }
}

// ---------------------------------------------------------------- aggregation
// R11: head = blockIdx&7 -> XCD (hw head slice L2-resident). Wave = 32
// (node,head) pairs x 2 channel-half lanes. Each lane owns 16 channels and
// iterates the node's true degree sequentially (degree-sorted perm => no
// divergence). acc is lane-private -> NO cross-lane reduction; dsum computed
// redundantly in both lanes. Edge stream software-pipelined one ahead.
__global__ __launch_bounds__(256, 8) void agg_kernel(const int* __restrict__ row_ptr,
                                                     const int* __restrict__ deg_arr,
                                                     const int* __restrict__ perm,
                                                     const u16* __restrict__ col,
                                                     const float* __restrict__ s_dst,
                                                     const float* __restrict__ s_src,
                                                     const _Float16* __restrict__ hw,
                                                     const float* __restrict__ bias,
                                                     _Float16* __restrict__ h_out) {
    const int wv   = threadIdx.x >> 6;
    const int lane = threadIdx.x & 63;
    const int head = blockIdx.x & (NB - 1);   // head == XCD
    const int ib   = blockIdx.x >> 3;
    const int nh   = lane >> 1;               // node slot 0..31
    const int lh   = lane & 1;                // channel half
    const int wid  = ib * 4 + wv;             // 0..WPH-1 per head

    const float* ssh = s_src + (size_t)head * N_NODES;
    const half8* hwp = (const half8*)(hw + (size_t)head * N_NODES * 32) + lh * 2;

    for (int grp = wid; grp < NGRP; grp += WPH) {
        int idx = grp * 32 + nh;
        int t = -1, start = 0, deg = 0;
        float sdv = 0.f;
        if (idx < N_NODES) {
            t = perm[idx];
            start = row_ptr[t];
            deg = deg_arr[t];
            sdv = s_dst[(size_t)head * N_NODES + t];
        }
        const u16* cb = col + start;

        float acc[16];
        #pragma unroll
        for (int i = 0; i < 16; i++) acc[i] = 0.f;
        float dsum = 0.f;

        // prologue: load edge 0 state
        int sn = (deg > 0) ? (int)cb[0] : 0;
        float ssv = ssh[sn];
        half8 va = hwp[(size_t)sn * 4];
        half8 vb = hwp[(size_t)sn * 4 + 1];

        for (int e = 0; e < deg; e++) {
            // issue next edge's loads (in-bounds clamp keeps data valid)
            int en = (e + 1 < deg) ? e + 1 : e;
            int snN = (int)cb[en];
            float ssN = ssh[snN];
            half8 vaN = hwp[(size_t)snN * 4];
            half8 vbN = hwp[(size_t)snN * 4 + 1];

            float a = sdv + ssv;
            a = (a > 0.f) ? a : NEG_SLOPE * a;
            float ex = __expf(a);
            dsum += ex;
            #pragma unroll
            for (int i = 0; i < 8; i++) acc[i]     += ex * (float)va[i];
            #pragma unroll
            for (int i = 0; i < 8; i++) acc[8 + i] += ex * (float)vb[i];

            sn = snN; ssv = ssN; va = vaN; vb = vbN;
        }

        if (t >= 0) {
            float inv = 1.f / (dsum + 1e-16f);
            const float* bp = bias + head * 32 + lh * 16;
            half8 o0, o1;
            #pragma unroll
            for (int i = 0; i < 8; i++) {
                float o = acc[i] * inv + bp[i];
                o = (o > 0.f) ? o : (__expf(o) - 1.f);
                o0[i] = (_Float16)o;
            }
            #pragma unroll
            for (int i = 0; i < 8; i++) {
                float o = acc[8 + i] * inv + bp[8 + i];
                o = (o > 0.f) ? o : (__expf(o) - 1.f);
                o1[i] = (_Float16)o;
            }
            half8* dst = (half8*)h_out + (size_t)t * 32 + head * 4 + lh * 2;
            dst[0] = o0;
            dst[1] = o1;
        }
    }
}

// ---------------------------------------------------------------- head
__global__ __launch_bounds__(256) void head_kernel(const _Float16* __restrict__ h,
                                                   const int* __restrict__ target_mask,
                                                   const float* __restrict__ W,
                                                   const float* __restrict__ b,
                                                   float* __restrict__ out) {
    int s = blockIdx.x;
    int t = threadIdx.x;
    int n0 = target_mask[s * 2 + 0];
    int n1 = target_mask[s * 2 + 1];
    float f0 = (float)h[(size_t)n0 * HID + t];
    float f1 = (float)h[(size_t)n1 * HID + t];
    float a0 = f0 * W[t * 3 + 0] + f1 * W[(t + 256) * 3 + 0];
    float a1 = f0 * W[t * 3 + 1] + f1 * W[(t + 256) * 3 + 1];
    float a2 = f0 * W[t * 3 + 2] + f1 * W[(t + 256) * 3 + 2];
    #pragma unroll
    for (int off = 32; off >= 1; off >>= 1) {
        a0 += __shfl_xor(a0, off);
        a1 += __shfl_xor(a1, off);
        a2 += __shfl_xor(a2, off);
    }
    __shared__ float red[4][3];
    int wv = t >> 6, ln = t & 63;
    if (ln == 0) { red[wv][0] = a0; red[wv][1] = a1; red[wv][2] = a2; }
    __syncthreads();
    if (t < 3) {
        out[s * 3 + t] = red[0][t] + red[1][t] + red[2][t] + red[3][t] + b[t];
    }
}

// ---------------------------------------------------------------- launch

extern "C" void kernel_launch(void* const* d_in, const int* in_sizes, int n_in,
                              void* d_out, int out_size, void* d_ws, size_t ws_size,
                              hipStream_t stream) {
    const float* x        = (const float*)d_in[0];
    const int*   eidx     = (const int*)  d_in[1];
    const int*   tmask    = (const int*)  d_in[2];
    const float* lin1_W   = (const float*)d_in[3];
    const float* lin1_b   = (const float*)d_in[4];
    const float* convs_W  = (const float*)d_in[5];
    const float* att_dst  = (const float*)d_in[6];
    const float* att_src  = (const float*)d_in[7];
    const float* convs_b  = (const float*)d_in[8];
    const float* lin3_W   = (const float*)d_in[9];
    const float* lin3_b   = (const float*)d_in[10];
    float* out = (float*)d_out;

    char* ws = (char*)d_ws;
    size_t off = 0;
    auto alloc = [&](size_t bytes) -> void* {
        void* p = ws + off;
        off = (off + bytes + 255) & ~(size_t)255;
        return p;
    };
    _Float16* xh   = (_Float16*)alloc((size_t)N_PAD * KP1 * 2);
    _Float16* h    = (_Float16*)alloc((size_t)N_PAD * HID * 2);
    _Float16* hw   = (_Float16*)alloc((size_t)N_PAD * HID * 2);   // head-major [8][N][32]
    _Float16* w1t  = (_Float16*)alloc((size_t)HID * KP1 * 2);
    _Float16* wct  = (_Float16*)alloc((size_t)LAYERS * HID * HID * 2);
    float* sdst    = (float*)alloc((size_t)HEADS * N_NODES * 4);  // head-major
    float* ssrc    = (float*)alloc((size_t)HEADS * N_NODES * 4);  // head-major
    int*   counts  = (int*)  alloc((size_t)N_NODES * 4);
    int*   rowptr  = (int*)  alloc((size_t)(N_NODES + 1) * 4);
    int*   cursor  = (int*)  alloc((size_t)N_NODES * 4);
    int*   perm    = (int*)  alloc((size_t)N_NODES * 4);
    u16*   col     = (u16*)  alloc((size_t)(EPAD + 32) * 2);
    ull*   bpart   = (ull*)  alloc((size_t)NB * BCAP * 8);
    int*   bcnt    = (int*)  alloc((size_t)NB * 4);
    int*   gcount  = (int*)  alloc((size_t)NBLK_P * NB * 4);
    int*   goff    = (int*)  alloc((size_t)NBLK_P * NB * 4);
    int*   bsum    = (int*)  alloc((size_t)NBLK_S * 4);
    int*   boff    = (int*)  alloc((size_t)NBLK_S * 4);
    int*   degcnt  = (int*)  alloc(256 * 4);
    int*   degoff  = (int*)  alloc(256 * 4);

    const int* src = eidx;
    const int* tgt = eidx + E_EDGES;

    // CSR build
    hipMemsetAsync(counts, 0, (size_t)N_NODES * 4, stream);
    hipMemsetAsync(degcnt, 0, 256 * 4, stream);
    part_count_kernel<<<NBLK_P, 256, 0, stream>>>(tgt, gcount);
    part_scan_kernel<<<1, NBLK_P, 0, stream>>>(gcount, goff, bcnt);
    part_scatter_kernel<<<NBLK_P, 256, 0, stream>>>(src, tgt, goff, bpart);
    count_edges_kernel<<<NBLK_B, 256, 0, stream>>>(bpart, bcnt, counts);
    scan1_kernel<<<NBLK_S, 256, 0, stream>>>(counts, rowptr, bsum);
    scan2_kernel<<<1, 256, 0, stream>>>(bsum, boff, rowptr);
    scan3_kernel<<<NBLK_S, 256, 0, stream>>>(rowptr, boff, cursor);
    fill_edges_kernel<<<NBLK_B, 256, 0, stream>>>(bpart, bcnt, cursor, col);

    // degree sort (perm ascending by degree)
    dsort_count_kernel<<<NBLK_S, 256, 0, stream>>>(counts, degcnt);
    dsort_scan_kernel<<<1, 256, 0, stream>>>(degcnt, degoff);
    dsort_fill_kernel<<<NBLK_S, 256, 0, stream>>>(counts, degoff, perm);

    // casts
    cast_x_kernel<<<(N_NODES * (KP1 / 8) + 255) / 256, 256, 0, stream>>>(x, xh);
    cast_w1_kernel<<<(HID * KP1 + 255) / 256, 256, 0, stream>>>(lin1_W, w1t);
    cast_wc_kernel<<<(LAYERS * HID * HID + 255) / 256, 256, 0, stream>>>(convs_W, wct);

    // lin1 (node-major output)
    gemm_mfma_kernel<<<dim3((N_NODES + 127) / 128, HID / 128), 256, 0, stream>>>(
        xh, w1t, lin1_b, h, N_NODES, KP1, 1, 0);

    for (int l = 0; l < LAYERS; l++) {
        // conv GEMM -> head-major hw
        gemm_mfma_kernel<<<dim3((N_NODES + 127) / 128, HID / 128), 256, 0, stream>>>(
            h, wct + (size_t)l * HID * HID, nullptr, hw, N_NODES, HID, 0, 1);
        score_kernel<<<256, 256, 0, stream>>>(
            hw, att_dst + (size_t)l * HEADS * OC, att_src + (size_t)l * HEADS * OC, sdst, ssrc);
        agg_kernel<<<NAGG, 256, 0, stream>>>(
            rowptr, counts, perm, col, sdst, ssrc, hw, convs_b + (size_t)l * HID, h);
    }

    head_kernel<<<BSAMP, 256, 0, stream>>>(h, tmask, lin3_W, lin3_b, out);
}

// Round 4
// 1141.304 us; speedup vs baseline: 1.5209x; 1.5209x over previous
//
#include <hip/hip_runtime.h>
#include <math.h>

#define N_NODES 50000
#define N_PAD   50048            // padded rows for 128-row GEMM tiles
#define E_EDGES 1600000
#define ETOT    (E_EDGES + N_NODES)
#define EPAD    (E_EDGES + 8 * N_NODES)   // CSR rows padded to multiple of 8
#define IN_DIM  300
#define KP1     320              // IN_DIM padded to mult of 32
#define HID     256
#define HEADS   8
#define OC      32
#define LAYERS  4
#define BSAMP   1024
#define NEG_SLOPE 0.2f

// XCD-bucketed CSR build
#define NB     8                 // buckets = XCDs (also heads in agg)
#define NPB    6250              // nodes per bucket (50000/8)
#define BCAP   262144            // per-bucket partition capacity (mean 206k)
#define NBLK_P 512               // partition blocks
#define NBLK_S 196               // scan blocks (50000/256 rounded up)
#define NBLK_B 2048              // bucket count/fill blocks (256 per bucket)
#define NAGG   2048              // agg blocks: head = blk&7 -> XCD-resident hw slice

typedef unsigned long long ull;
typedef unsigned short u16;
typedef _Float16 half8 __attribute__((ext_vector_type(8)));
typedef _Float16 half4v __attribute__((ext_vector_type(4)));
typedef float f32x4 __attribute__((ext_vector_type(4)));

#define GLDS16(g, l) __builtin_amdgcn_global_load_lds( \
    (const __attribute__((address_space(1))) void*)(g), \
    (__attribute__((address_space(3))) void*)(l), 16, 0, 0)

// ---------------------------------------------------------------- CSR build
// Two-pass block-local radix partition by tgt bucket. No global atomics.

__global__ __launch_bounds__(256) void part_count_kernel(const int* __restrict__ tgt,
                                                         int* __restrict__ gcount) {
    __shared__ int cnt[NB];
    if (threadIdx.x < NB) cnt[threadIdx.x] = 0;
    __syncthreads();
    const int chunk = (ETOT + NBLK_P - 1) / NBLK_P;
    int beg = blockIdx.x * chunk;
    int end = min(beg + chunk, ETOT);
    for (int e = beg + threadIdx.x; e < end; e += 256) {
        int t_ = (e < E_EDGES) ? tgt[e] : (e - E_EDGES);
        atomicAdd(&cnt[t_ / NPB], 1);
    }
    __syncthreads();
    if (threadIdx.x < NB) gcount[blockIdx.x * NB + threadIdx.x] = cnt[threadIdx.x];
}

// parallel scan over NBLK_P block-counts x NB buckets (1 block, 512 threads)
__global__ __launch_bounds__(512) void part_scan_kernel(const int* __restrict__ gcount,
                                                        int* __restrict__ goff,
                                                        int* __restrict__ bcnt) {
    __shared__ int arr[NBLK_P][NB];
    int k = threadIdx.x;
    int4 a = ((const int4*)gcount)[k * 2];
    int4 b = ((const int4*)gcount)[k * 2 + 1];
    int own[NB] = {a.x, a.y, a.z, a.w, b.x, b.y, b.z, b.w};
    #pragma unroll
    for (int j = 0; j < NB; j++) arr[k][j] = own[j];
    __syncthreads();
    for (int off = 1; off < NBLK_P; off <<= 1) {
        int tmp[NB];
        #pragma unroll
        for (int j = 0; j < NB; j++) tmp[j] = (k >= off) ? arr[k - off][j] : 0;
        __syncthreads();
        #pragma unroll
        for (int j = 0; j < NB; j++) arr[k][j] += tmp[j];
        __syncthreads();
    }
    int ex[NB];
    #pragma unroll
    for (int j = 0; j < NB; j++) ex[j] = arr[k][j] - own[j];   // exclusive
    ((int4*)goff)[k * 2]     = make_int4(ex[0], ex[1], ex[2], ex[3]);
    ((int4*)goff)[k * 2 + 1] = make_int4(ex[4], ex[5], ex[6], ex[7]);
    if (k == NBLK_P - 1) {
        #pragma unroll
        for (int j = 0; j < NB; j++) bcnt[j] = arr[k][j];
    }
}

__global__ __launch_bounds__(256) void part_scatter_kernel(const int* __restrict__ src,
                                                           const int* __restrict__ tgt,
                                                           const int* __restrict__ goff,
                                                           ull* __restrict__ bpart) {
    __shared__ int cur[NB];
    if (threadIdx.x < NB) cur[threadIdx.x] = goff[blockIdx.x * NB + threadIdx.x];
    __syncthreads();
    const int chunk = (ETOT + NBLK_P - 1) / NBLK_P;
    int beg = blockIdx.x * chunk;
    int end = min(beg + chunk, ETOT);
    for (int e = beg + threadIdx.x; e < end; e += 256) {
        int s_, t_;
        if (e < E_EDGES) { s_ = src[e]; t_ = tgt[e]; }
        else             { s_ = t_ = e - E_EDGES; }
        int b = t_ / NPB;
        int pos = atomicAdd(&cur[b], 1);
        bpart[(size_t)b * BCAP + pos] = ((ull)(unsigned)t_ << 32) | (unsigned)s_;
    }
}

// per-bucket degree count (blockIdx%8 = bucket -> XCD-local counts lines)
__global__ __launch_bounds__(256) void count_edges_kernel(const ull* __restrict__ bpart,
                                                          const int* __restrict__ bcnt,
                                                          int* counts) {
    int b = blockIdx.x & (NB - 1);
    int ib = blockIdx.x >> 3;
    int nblk = gridDim.x >> 3;
    int nb = bcnt[b];
    const ull* bp = bpart + (size_t)b * BCAP;
    for (int i = ib * 256 + threadIdx.x; i < nb; i += nblk * 256)
        atomicAdd(&counts[(int)(bp[i] >> 32)], 1);
}

// ---------------- parallel scan of padded counts (3 tiny kernels) ----------
__global__ __launch_bounds__(256) void scan1_kernel(const int* __restrict__ counts,
                                                    int* __restrict__ row_ptr,
                                                    int* __restrict__ bsum) {
    __shared__ int sums[256];
    int t = threadIdx.x;
    int i = blockIdx.x * 256 + t;
    int c = (i < N_NODES) ? ((counts[i] + 7) & ~7) : 0;
    sums[t] = c;
    __syncthreads();
    for (int off = 1; off < 256; off <<= 1) {
        int a = sums[t];
        int u = (t >= off) ? sums[t - off] : 0;
        __syncthreads();
        sums[t] = a + u;
        __syncthreads();
    }
    if (i < N_NODES) row_ptr[i] = sums[t] - c;   // local exclusive
    if (t == 255) bsum[blockIdx.x] = sums[255];
}

__global__ __launch_bounds__(256) void scan2_kernel(const int* __restrict__ bsum,
                                                    int* __restrict__ boff,
                                                    int* __restrict__ row_ptr) {
    __shared__ int sums[256];
    int t = threadIdx.x;
    int b = (t < NBLK_S) ? bsum[t] : 0;
    sums[t] = b;
    __syncthreads();
    for (int off = 1; off < 256; off <<= 1) {
        int a = sums[t];
        int u = (t >= off) ? sums[t - off] : 0;
        __syncthreads();
        sums[t] = a + u;
        __syncthreads();
    }
    if (t < NBLK_S) boff[t] = sums[t] - b;
    if (t == 255) row_ptr[N_NODES] = sums[255];
}

__global__ __launch_bounds__(256) void scan3_kernel(int* __restrict__ row_ptr,
                                                    const int* __restrict__ boff,
                                                    int* __restrict__ cursor) {
    int i = blockIdx.x * 256 + threadIdx.x;
    if (i >= N_NODES) return;
    int v = row_ptr[i] + boff[blockIdx.x];
    row_ptr[i] = v;
    cursor[i]  = v;
}

// per-bucket scatter into col (cursor + col lines XCD-local); col is u16
__global__ __launch_bounds__(256) void fill_edges_kernel(const ull* __restrict__ bpart,
                                                         const int* __restrict__ bcnt,
                                                         int* cursor, u16* __restrict__ col) {
    int b = blockIdx.x & (NB - 1);
    int ib = blockIdx.x >> 3;
    int nblk = gridDim.x >> 3;
    int nb = bcnt[b];
    const ull* bp = bpart + (size_t)b * BCAP;
    for (int i = ib * 256 + threadIdx.x; i < nb; i += nblk * 256) {
        ull pk = bp[i];
        int t_ = (int)(pk >> 32);
        int s_ = (int)pk;
        int pos = atomicAdd(&cursor[t_], 1);
        col[pos] = (u16)s_;
    }
}

// fill pad slots with the row's own node id (valid index; ex forced 0 later)
__global__ __launch_bounds__(256) void pad_edges_kernel(const int* __restrict__ cursor,
                                                        const int* __restrict__ row_ptr,
                                                        u16* __restrict__ col) {
    int i = blockIdx.x * 256 + threadIdx.x;
    if (i >= N_NODES) return;
    int e = cursor[i];            // true end after fill
    int pe = row_ptr[i + 1];      // padded end
    for (; e < pe; e++) col[e] = (u16)i;
}

// ---------------------------------------------------------------- fp32 -> fp16 casts

__global__ __launch_bounds__(256) void cast_x_kernel(const float* __restrict__ x, _Float16* __restrict__ xh) {
    int i = blockIdx.x * 256 + threadIdx.x;          // over 50000*40 half8s
    if (i >= N_NODES * (KP1 / 8)) return;
    int r = i / (KP1 / 8), c8 = i % (KP1 / 8);
    half8 o;
    const float4* xr = (const float4*)(x + (size_t)r * IN_DIM);
    if (c8 < 37) {
        float4 u = xr[c8 * 2], v = xr[c8 * 2 + 1];
        o[0] = (_Float16)u.x; o[1] = (_Float16)u.y; o[2] = (_Float16)u.z; o[3] = (_Float16)u.w;
        o[4] = (_Float16)v.x; o[5] = (_Float16)v.y; o[6] = (_Float16)v.z; o[7] = (_Float16)v.w;
    } else if (c8 == 37) {
        float4 u = xr[74];
        o[0] = (_Float16)u.x; o[1] = (_Float16)u.y; o[2] = (_Float16)u.z; o[3] = (_Float16)u.w;
        o[4] = o[5] = o[6] = o[7] = (_Float16)0.f;
    } else {
        #pragma unroll
        for (int j = 0; j < 8; j++) o[j] = (_Float16)0.f;
    }
    ((half8*)xh)[i] = o;
}

__global__ __launch_bounds__(256) void cast_w1_kernel(const float* __restrict__ W, _Float16* __restrict__ Wt) {
    int i = blockIdx.x * 256 + threadIdx.x;
    if (i >= HID * KP1) return;
    int n = i / KP1, k = i % KP1;
    float v = (k < IN_DIM) ? W[(size_t)k * HID + n] : 0.f;
    Wt[i] = (_Float16)v;
}

__global__ __launch_bounds__(256) void cast_wc_kernel(const float* __restrict__ W, _Float16* __restrict__ Wt) {
    int i = blockIdx.x * 256 + threadIdx.x;
    if (i >= LAYERS * HID * HID) return;
    int l = i / (HID * HID);
    int r = i % (HID * HID);
    int n = r / HID, k = r % HID;
    Wt[i] = (_Float16)W[(size_t)l * HID * HID + (size_t)k * HID + n];
}

// ---------------------------------------------------------------- fp16 MFMA GEMM
// headmajor=1 writes C as [head][node][32] (stride N_NODES rows per head slice)
__global__ __launch_bounds__(256) void gemm_mfma_kernel(const _Float16* __restrict__ A,
                                                        const _Float16* __restrict__ Wt,
                                                        const float* __restrict__ bias,
                                                        _Float16* __restrict__ C,
                                                        int M, int Kp, int addbias,
                                                        int headmajor) {
    __shared__ _Float16 As[128][32];
    __shared__ _Float16 Bs[128][32];
    const int tid = threadIdx.x;
    const int m0 = blockIdx.x * 128;
    const int n0 = blockIdx.y * 128;
    const int w = tid >> 6, lane = tid & 63;
    const int wm = (w & 1) * 64, wn = (w >> 1) * 64;
    const int quad = lane >> 4, m16 = lane & 15;

    f32x4 acc[4][4];
    #pragma unroll
    for (int i = 0; i < 4; i++)
        #pragma unroll
        for (int j = 0; j < 4; j++)
            acc[i][j] = (f32x4){0.f, 0.f, 0.f, 0.f};

    char* lA = (char*)&As[0][0] + w * 1024;   // wave-uniform LDS bases
    char* lB = (char*)&Bs[0][0] + w * 1024;

    for (int k0 = 0; k0 < Kp; k0 += 32) {
        #pragma unroll
        for (int i = 0; i < 2; i++) {
            int seg = tid + i * 256;
            int row = seg >> 2, off = seg & 3;
            GLDS16(&A[(size_t)(m0 + row) * Kp + k0 + off * 8], lA + i * 4096);
            GLDS16(&Wt[(size_t)(n0 + row) * Kp + k0 + off * 8], lB + i * 4096);
        }
        __syncthreads();

        half8 af[4], bf[4];
        #pragma unroll
        for (int i = 0; i < 4; i++) {
            af[i] = *(const half8*)&As[wm + i * 16 + m16][quad * 8];
            bf[i] = *(const half8*)&Bs[wn + i * 16 + m16][quad * 8];
        }
        #pragma unroll
        for (int mi = 0; mi < 4; mi++)
            #pragma unroll
            for (int ni = 0; ni < 4; ni++)
                acc[mi][ni] = __builtin_amdgcn_mfma_f32_16x16x32_f16(af[mi], bf[ni], acc[mi][ni], 0, 0, 0);
        __syncthreads();
    }

    #pragma unroll
    for (int mi = 0; mi < 4; mi++) {
        #pragma unroll
        for (int r = 0; r < 4; r++) {
            int row = m0 + wm + mi * 16 + quad * 4 + r;
            if (row < M) {
                #pragma unroll
                for (int ni = 0; ni < 4; ni++) {
                    int colg = n0 + wn + ni * 16 + m16;
                    float v = acc[mi][ni][r];
                    if (addbias) v += bias[colg];
                    if (headmajor) {
                        int hd = colg >> 5, oc = colg & 31;
                        C[((size_t)hd * N_NODES + row) * 32 + oc] = (_Float16)v;
                    } else {
                        C[(size_t)row * HID + colg] = (_Float16)v;
                    }
                }
            }
        }
    }
}

// ---------------------------------------------------------------- attention scores
// hw is head-major [head][node][32]; s arrays head-major [head][node].
// Wave = 8 nodes; lane = (node nd=lane>>3, head hd=lane&7).
__global__ __launch_bounds__(256) void score_kernel(const _Float16* __restrict__ hw,
                                                    const float* __restrict__ att_dst,
                                                    const float* __restrict__ att_src,
                                                    float* __restrict__ s_dst,
                                                    float* __restrict__ s_src) {
    int wv = threadIdx.x >> 6, lane = threadIdx.x & 63;
    int nd = lane >> 3, hd = lane & 7;
    float4 ad[8], as4[8];
    const float4* A4d = (const float4*)att_dst;
    const float4* A4s = (const float4*)att_src;
    #pragma unroll
    for (int j = 0; j < 8; j++) { ad[j] = A4d[hd * 8 + j]; as4[j] = A4s[hd * 8 + j]; }
    const half8* hw8 = (const half8*)hw;
    int nwaves = gridDim.x * 4;
    for (int g = blockIdx.x * 4 + wv; g < N_NODES / 8; g += nwaves) {
        int node = g * 8 + nd;
        float sd = 0.f, ss = 0.f;
        #pragma unroll
        for (int k = 0; k < 4; k++) {
            half8 v = hw8[((size_t)hd * N_NODES + node) * 4 + k];
            #pragma unroll
            for (int i = 0; i < 8; i++) {
                float f = (float)v[i];
                int q = k * 8 + i;
                sd += f * ((const float*)&ad[q >> 2])[q & 3];
                ss += f * ((const float*)&as4[q >> 2])[q & 3];
            }
        }
        s_dst[(size_t)hd * N_NODES + node] = sd;
        s_src[(size_t)hd * N_NODES + node] = ss;
    }
}

// ---------------------------------------------------------------- aggregation
// R12: R10's L2-resident moving window (one node per wave, stride NW, head =
// blockIdx&7 -> XCD) + lean VALU: lane = 8 edge slots (es) x 8 channel-lanes
// (cl owns 4 ch = 8B of the 64B row). Reduction = 3 rounds x 5 values.
// Full edge state (col/ssrc/hw) software-pipelined one group ahead.
// 32-bit offsets from pre-biased bases -> saddr addressing.
__global__ __launch_bounds__(256, 8) void agg_kernel(const int* __restrict__ row_ptr,
                                                     const int* __restrict__ deg_arr,
                                                     const u16* __restrict__ col,
                                                     const float* __restrict__ s_dst,
                                                     const float* __restrict__ s_src,
                                                     const _Float16* __restrict__ hw,
                                                     const float* __restrict__ bias,
                                                     _Float16* __restrict__ h_out) {
    const int wv   = threadIdx.x >> 6;
    const int lane = threadIdx.x & 63;
    const int head = blockIdx.x & (NB - 1);   // head == XCD
    const int ib   = blockIdx.x >> 3;         // 0..255 within head
    const int es = lane >> 3;                 // edge slot 0..7 (lane bits 3..5)
    const int cl = lane & 7;                  // channel-eighth: 4 ch (8B)
    const int wid = ib * 4 + wv;              // 0..1023
    const int NW  = (NAGG / NB) * 4;          // 1024 waves per head

    const float* sdh = s_dst + (size_t)head * N_NODES;
    const float* ssh = s_src + (size_t)head * N_NODES;
    const char*  hwb = (const char*)(hw + (size_t)head * N_NODES * 32) + cl * 8;

    const float* bp = bias + head * 32 + cl * 4;
    float b0 = bp[0], b1 = bp[1], b2 = bp[2], b3 = bp[3];

    for (int t = wid; t < N_NODES; t += NW) {
        int start = row_ptr[t];               // uniform -> scalar loads
        int pdeg  = row_ptr[t + 1] - start;
        int deg   = deg_arr[t];
        float sdv = sdh[t];
        const u16* cb = col + start;
        int ngrp = pdeg >> 3;                 // pdeg is a multiple of 8, >= 8

        float dsum = 0.f;
        float a0 = 0.f, a1 = 0.f, a2 = 0.f, a3 = 0.f;

        // prologue: group 0 state
        int sn = (int)cb[es];
        float ssv = ssh[(unsigned)sn];
        half4v v = *(const half4v*)(hwb + ((unsigned)sn << 6));

        for (int g = 0; g < ngrp; g++) {
            int slot = g * 8 + es;
            // issue next group's loads (pad slots hold valid self-id)
            int snN = (g + 1 < ngrp) ? (int)cb[slot + 8] : 0;
            float ssN = ssh[(unsigned)snN];
            half4v vN = *(const half4v*)(hwb + ((unsigned)snN << 6));

            float a = sdv + ssv;
            a = (a > 0.f) ? a : NEG_SLOPE * a;
            float ex = (slot < deg) ? __expf(a) : 0.f;
            dsum += ex;
            a0 += ex * (float)v[0];
            a1 += ex * (float)v[1];
            a2 += ex * (float)v[2];
            a3 += ex * (float)v[3];

            sn = snN; ssv = ssN; v = vN;
        }

        // reduce across the 8 edge slots (lane bits 3,4,5)
        #pragma unroll
        for (int off = 8; off <= 32; off <<= 1) {
            dsum += __shfl_xor(dsum, off);
            a0 += __shfl_xor(a0, off);
            a1 += __shfl_xor(a1, off);
            a2 += __shfl_xor(a2, off);
            a3 += __shfl_xor(a3, off);
        }

        if (es == 0) {
            float inv = 1.f / (dsum + 1e-16f);
            float o0 = a0 * inv + b0;
            float o1 = a1 * inv + b1;
            float o2 = a2 * inv + b2;
            float o3 = a3 * inv + b3;
            o0 = (o0 > 0.f) ? o0 : (__expf(o0) - 1.f);
            o1 = (o1 > 0.f) ? o1 : (__expf(o1) - 1.f);
            o2 = (o2 > 0.f) ? o2 : (__expf(o2) - 1.f);
            o3 = (o3 > 0.f) ? o3 : (__expf(o3) - 1.f);
            half4v ov;
            ov[0] = (_Float16)o0; ov[1] = (_Float16)o1;
            ov[2] = (_Float16)o2; ov[3] = (_Float16)o3;
            *(half4v*)(h_out + (size_t)t * HID + head * 32 + cl * 4) = ov;
        }
    }
}

// ---------------------------------------------------------------- head
__global__ __launch_bounds__(256) void head_kernel(const _Float16* __restrict__ h,
                                                   const int* __restrict__ target_mask,
                                                   const float* __restrict__ W,
                                                   const float* __restrict__ b,
                                                   float* __restrict__ out) {
    int s = blockIdx.x;
    int t = threadIdx.x;
    int n0 = target_mask[s * 2 + 0];
    int n1 = target_mask[s * 2 + 1];
    float f0 = (float)h[(size_t)n0 * HID + t];
    float f1 = (float)h[(size_t)n1 * HID + t];
    float a0 = f0 * W[t * 3 + 0] + f1 * W[(t + 256) * 3 + 0];
    float a1 = f0 * W[t * 3 + 1] + f1 * W[(t + 256) * 3 + 1];
    float a2 = f0 * W[t * 3 + 2] + f1 * W[(t + 256) * 3 + 2];
    #pragma unroll
    for (int off = 32; off >= 1; off >>= 1) {
        a0 += __shfl_xor(a0, off);
        a1 += __shfl_xor(a1, off);
        a2 += __shfl_xor(a2, off);
    }
    __shared__ float red[4][3];
    int wv = t >> 6, ln = t & 63;
    if (ln == 0) { red[wv][0] = a0; red[wv][1] = a1; red[wv][2] = a2; }
    __syncthreads();
    if (t < 3) {
        out[s * 3 + t] = red[0][t] + red[1][t] + red[2][t] + red[3][t] + b[t];
    }
}

// ---------------------------------------------------------------- launch

extern "C" void kernel_launch(void* const* d_in, const int* in_sizes, int n_in,
                              void* d_out, int out_size, void* d_ws, size_t ws_size,
                              hipStream_t stream) {
    const float* x        = (const float*)d_in[0];
    const int*   eidx     = (const int*)  d_in[1];
    const int*   tmask    = (const int*)  d_in[2];
    const float* lin1_W   = (const float*)d_in[3];
    const float* lin1_b   = (const float*)d_in[4];
    const float* convs_W  = (const float*)d_in[5];
    const float* att_dst  = (const float*)d_in[6];
    const float* att_src  = (const float*)d_in[7];
    const float* convs_b  = (const float*)d_in[8];
    const float* lin3_W   = (const float*)d_in[9];
    const float* lin3_b   = (const float*)d_in[10];
    float* out = (float*)d_out;

    char* ws = (char*)d_ws;
    size_t off = 0;
    auto alloc = [&](size_t bytes) -> void* {
        void* p = ws + off;
        off = (off + bytes + 255) & ~(size_t)255;
        return p;
    };
    _Float16* xh   = (_Float16*)alloc((size_t)N_PAD * KP1 * 2);
    _Float16* h    = (_Float16*)alloc((size_t)N_PAD * HID * 2);
    _Float16* hw   = (_Float16*)alloc((size_t)N_PAD * HID * 2);   // head-major [8][N][32]
    _Float16* w1t  = (_Float16*)alloc((size_t)HID * KP1 * 2);
    _Float16* wct  = (_Float16*)alloc((size_t)LAYERS * HID * HID * 2);
    float* sdst    = (float*)alloc((size_t)HEADS * N_NODES * 4);  // head-major
    float* ssrc    = (float*)alloc((size_t)HEADS * N_NODES * 4);  // head-major
    int*   counts  = (int*)  alloc((size_t)N_NODES * 4);
    int*   rowptr  = (int*)  alloc((size_t)(N_NODES + 1) * 4);
    int*   cursor  = (int*)  alloc((size_t)N_NODES * 4);
    u16*   col     = (u16*)  alloc((size_t)(EPAD + 32) * 2);
    ull*   bpart   = (ull*)  alloc((size_t)NB * BCAP * 8);
    int*   bcnt    = (int*)  alloc((size_t)NB * 4);
    int*   gcount  = (int*)  alloc((size_t)NBLK_P * NB * 4);
    int*   goff    = (int*)  alloc((size_t)NBLK_P * NB * 4);
    int*   bsum    = (int*)  alloc((size_t)NBLK_S * 4);
    int*   boff    = (int*)  alloc((size_t)NBLK_S * 4);

    const int* src = eidx;
    const int* tgt = eidx + E_EDGES;

    // CSR build
    hipMemsetAsync(counts, 0, (size_t)N_NODES * 4, stream);
    part_count_kernel<<<NBLK_P, 256, 0, stream>>>(tgt, gcount);
    part_scan_kernel<<<1, NBLK_P, 0, stream>>>(gcount, goff, bcnt);
    part_scatter_kernel<<<NBLK_P, 256, 0, stream>>>(src, tgt, goff, bpart);
    count_edges_kernel<<<NBLK_B, 256, 0, stream>>>(bpart, bcnt, counts);
    scan1_kernel<<<NBLK_S, 256, 0, stream>>>(counts, rowptr, bsum);
    scan2_kernel<<<1, 256, 0, stream>>>(bsum, boff, rowptr);
    scan3_kernel<<<NBLK_S, 256, 0, stream>>>(rowptr, boff, cursor);
    fill_edges_kernel<<<NBLK_B, 256, 0, stream>>>(bpart, bcnt, cursor, col);
    pad_edges_kernel<<<(N_NODES + 255) / 256, 256, 0, stream>>>(cursor, rowptr, col);

    // casts
    cast_x_kernel<<<(N_NODES * (KP1 / 8) + 255) / 256, 256, 0, stream>>>(x, xh);
    cast_w1_kernel<<<(HID * KP1 + 255) / 256, 256, 0, stream>>>(lin1_W, w1t);
    cast_wc_kernel<<<(LAYERS * HID * HID + 255) / 256, 256, 0, stream>>>(convs_W, wct);

    // lin1 (node-major output)
    gemm_mfma_kernel<<<dim3((N_NODES + 127) / 128, HID / 128), 256, 0, stream>>>(
        xh, w1t, lin1_b, h, N_NODES, KP1, 1, 0);

    for (int l = 0; l < LAYERS; l++) {
        // conv GEMM -> head-major hw
        gemm_mfma_kernel<<<dim3((N_NODES + 127) / 128, HID / 128), 256, 0, stream>>>(
            h, wct + (size_t)l * HID * HID, nullptr, hw, N_NODES, HID, 0, 1);
        score_kernel<<<256, 256, 0, stream>>>(
            hw, att_dst + (size_t)l * HEADS * OC, att_src + (size_t)l * HEADS * OC, sdst, ssrc);
        agg_kernel<<<NAGG, 256, 0, stream>>>(
            rowptr, counts, col, sdst, ssrc, hw, convs_b + (size_t)l * HID, h);
    }

    head_kernel<<<BSAMP, 256, 0, stream>>>(h, tmask, lin3_W, lin3_b, out);
}

// Round 5
// 1124.143 us; speedup vs baseline: 1.5441x; 1.0153x over previous
//
#include <hip/hip_runtime.h>
#include <math.h>

#define N_NODES 50000
#define N_PAD   50048            // padded rows for 128-row GEMM tiles
#define E_EDGES 1600000
#define ETOT    (E_EDGES + N_NODES)
#define EPAD    (E_EDGES + 8 * N_NODES)   // CSR rows padded to multiple of 8
#define IN_DIM  300
#define KP1     320              // IN_DIM padded to mult of 32
#define HID     256
#define HEADS   8
#define OC      32
#define LAYERS  4
#define BSAMP   1024
#define NEG_SLOPE 0.2f

// XCD-bucketed CSR build
#define NB     8                 // buckets = XCDs (also heads in agg)
#define NPB    6250              // nodes per bucket (50000/8)
#define BCAP   262144            // per-bucket partition capacity (mean 206k)
#define NBLK_P 512               // partition blocks
#define NBLK_S 196               // scan blocks (50000/256 rounded up)
#define NBLK_B 2048              // bucket count/fill blocks (256 per bucket)
#define NAGG   2048              // agg blocks: head = blk&7 -> XCD-resident hw slice

typedef unsigned long long ull;
typedef unsigned short u16;
typedef _Float16 half8 __attribute__((ext_vector_type(8)));
typedef _Float16 half4v __attribute__((ext_vector_type(4)));
typedef float f32x4 __attribute__((ext_vector_type(4)));

#define GLDS16(g, l) __builtin_amdgcn_global_load_lds( \
    (const __attribute__((address_space(1))) void*)(g), \
    (__attribute__((address_space(3))) void*)(l), 16, 0, 0)

// ---------------------------------------------------------------- CSR build
// Two-pass block-local radix partition by tgt bucket. No global atomics.

__global__ __launch_bounds__(256) void part_count_kernel(const int* __restrict__ tgt,
                                                         int* __restrict__ gcount) {
    __shared__ int cnt[NB];
    if (threadIdx.x < NB) cnt[threadIdx.x] = 0;
    __syncthreads();
    const int chunk = (ETOT + NBLK_P - 1) / NBLK_P;
    int beg = blockIdx.x * chunk;
    int end = min(beg + chunk, ETOT);
    for (int e = beg + threadIdx.x; e < end; e += 256) {
        int t_ = (e < E_EDGES) ? tgt[e] : (e - E_EDGES);
        atomicAdd(&cnt[t_ / NPB], 1);
    }
    __syncthreads();
    if (threadIdx.x < NB) gcount[blockIdx.x * NB + threadIdx.x] = cnt[threadIdx.x];
}

// parallel scan over NBLK_P block-counts x NB buckets (1 block, 512 threads)
__global__ __launch_bounds__(512) void part_scan_kernel(const int* __restrict__ gcount,
                                                        int* __restrict__ goff,
                                                        int* __restrict__ bcnt) {
    __shared__ int arr[NBLK_P][NB];
    int k = threadIdx.x;
    int4 a = ((const int4*)gcount)[k * 2];
    int4 b = ((const int4*)gcount)[k * 2 + 1];
    int own[NB] = {a.x, a.y, a.z, a.w, b.x, b.y, b.z, b.w};
    #pragma unroll
    for (int j = 0; j < NB; j++) arr[k][j] = own[j];
    __syncthreads();
    for (int off = 1; off < NBLK_P; off <<= 1) {
        int tmp[NB];
        #pragma unroll
        for (int j = 0; j < NB; j++) tmp[j] = (k >= off) ? arr[k - off][j] : 0;
        __syncthreads();
        #pragma unroll
        for (int j = 0; j < NB; j++) arr[k][j] += tmp[j];
        __syncthreads();
    }
    int ex[NB];
    #pragma unroll
    for (int j = 0; j < NB; j++) ex[j] = arr[k][j] - own[j];   // exclusive
    ((int4*)goff)[k * 2]     = make_int4(ex[0], ex[1], ex[2], ex[3]);
    ((int4*)goff)[k * 2 + 1] = make_int4(ex[4], ex[5], ex[6], ex[7]);
    if (k == NBLK_P - 1) {
        #pragma unroll
        for (int j = 0; j < NB; j++) bcnt[j] = arr[k][j];
    }
}

__global__ __launch_bounds__(256) void part_scatter_kernel(const int* __restrict__ src,
                                                           const int* __restrict__ tgt,
                                                           const int* __restrict__ goff,
                                                           ull* __restrict__ bpart) {
    __shared__ int cur[NB];
    if (threadIdx.x < NB) cur[threadIdx.x] = goff[blockIdx.x * NB + threadIdx.x];
    __syncthreads();
    const int chunk = (ETOT + NBLK_P - 1) / NBLK_P;
    int beg = blockIdx.x * chunk;
    int end = min(beg + chunk, ETOT);
    for (int e = beg + threadIdx.x; e < end; e += 256) {
        int s_, t_;
        if (e < E_EDGES) { s_ = src[e]; t_ = tgt[e]; }
        else             { s_ = t_ = e - E_EDGES; }
        int b = t_ / NPB;
        int pos = atomicAdd(&cur[b], 1);
        bpart[(size_t)b * BCAP + pos] = ((ull)(unsigned)t_ << 32) | (unsigned)s_;
    }
}

// per-bucket degree count (blockIdx%8 = bucket -> XCD-local counts lines)
__global__ __launch_bounds__(256) void count_edges_kernel(const ull* __restrict__ bpart,
                                                          const int* __restrict__ bcnt,
                                                          int* counts) {
    int b = blockIdx.x & (NB - 1);
    int ib = blockIdx.x >> 3;
    int nblk = gridDim.x >> 3;
    int nb = bcnt[b];
    const ull* bp = bpart + (size_t)b * BCAP;
    for (int i = ib * 256 + threadIdx.x; i < nb; i += nblk * 256)
        atomicAdd(&counts[(int)(bp[i] >> 32)], 1);
}

// ---------------- parallel scan of padded counts (3 tiny kernels) ----------
__global__ __launch_bounds__(256) void scan1_kernel(const int* __restrict__ counts,
                                                    int* __restrict__ row_ptr,
                                                    int* __restrict__ bsum) {
    __shared__ int sums[256];
    int t = threadIdx.x;
    int i = blockIdx.x * 256 + t;
    int c = (i < N_NODES) ? ((counts[i] + 7) & ~7) : 0;
    sums[t] = c;
    __syncthreads();
    for (int off = 1; off < 256; off <<= 1) {
        int a = sums[t];
        int u = (t >= off) ? sums[t - off] : 0;
        __syncthreads();
        sums[t] = a + u;
        __syncthreads();
    }
    if (i < N_NODES) row_ptr[i] = sums[t] - c;   // local exclusive
    if (t == 255) bsum[blockIdx.x] = sums[255];
}

__global__ __launch_bounds__(256) void scan2_kernel(const int* __restrict__ bsum,
                                                    int* __restrict__ boff,
                                                    int* __restrict__ row_ptr) {
    __shared__ int sums[256];
    int t = threadIdx.x;
    int b = (t < NBLK_S) ? bsum[t] : 0;
    sums[t] = b;
    __syncthreads();
    for (int off = 1; off < 256; off <<= 1) {
        int a = sums[t];
        int u = (t >= off) ? sums[t - off] : 0;
        __syncthreads();
        sums[t] = a + u;
        __syncthreads();
    }
    if (t < NBLK_S) boff[t] = sums[t] - b;
    if (t == 255) row_ptr[N_NODES] = sums[255];
}

__global__ __launch_bounds__(256) void scan3_kernel(int* __restrict__ row_ptr,
                                                    const int* __restrict__ boff,
                                                    int* __restrict__ cursor) {
    int i = blockIdx.x * 256 + threadIdx.x;
    if (i >= N_NODES) return;
    int v = row_ptr[i] + boff[blockIdx.x];
    row_ptr[i] = v;
    cursor[i]  = v;
}

// per-bucket scatter into col (cursor + col lines XCD-local); col is u16
__global__ __launch_bounds__(256) void fill_edges_kernel(const ull* __restrict__ bpart,
                                                         const int* __restrict__ bcnt,
                                                         int* cursor, u16* __restrict__ col) {
    int b = blockIdx.x & (NB - 1);
    int ib = blockIdx.x >> 3;
    int nblk = gridDim.x >> 3;
    int nb = bcnt[b];
    const ull* bp = bpart + (size_t)b * BCAP;
    for (int i = ib * 256 + threadIdx.x; i < nb; i += nblk * 256) {
        ull pk = bp[i];
        int t_ = (int)(pk >> 32);
        int s_ = (int)pk;
        int pos = atomicAdd(&cursor[t_], 1);
        col[pos] = (u16)s_;
    }
}

// fill pad slots with the row's own node id (valid index; ex forced 0 later)
__global__ __launch_bounds__(256) void pad_edges_kernel(const int* __restrict__ cursor,
                                                        const int* __restrict__ row_ptr,
                                                        u16* __restrict__ col) {
    int i = blockIdx.x * 256 + threadIdx.x;
    if (i >= N_NODES) return;
    int e = cursor[i];            // true end after fill
    int pe = row_ptr[i + 1];      // padded end
    for (; e < pe; e++) col[e] = (u16)i;
}

// ---------------------------------------------------------------- fp32 -> fp16 casts

__global__ __launch_bounds__(256) void cast_x_kernel(const float* __restrict__ x, _Float16* __restrict__ xh) {
    int i = blockIdx.x * 256 + threadIdx.x;          // over 50000*40 half8s
    if (i >= N_NODES * (KP1 / 8)) return;
    int r = i / (KP1 / 8), c8 = i % (KP1 / 8);
    half8 o;
    const float4* xr = (const float4*)(x + (size_t)r * IN_DIM);
    if (c8 < 37) {
        float4 u = xr[c8 * 2], v = xr[c8 * 2 + 1];
        o[0] = (_Float16)u.x; o[1] = (_Float16)u.y; o[2] = (_Float16)u.z; o[3] = (_Float16)u.w;
        o[4] = (_Float16)v.x; o[5] = (_Float16)v.y; o[6] = (_Float16)v.z; o[7] = (_Float16)v.w;
    } else if (c8 == 37) {
        float4 u = xr[74];
        o[0] = (_Float16)u.x; o[1] = (_Float16)u.y; o[2] = (_Float16)u.z; o[3] = (_Float16)u.w;
        o[4] = o[5] = o[6] = o[7] = (_Float16)0.f;
    } else {
        #pragma unroll
        for (int j = 0; j < 8; j++) o[j] = (_Float16)0.f;
    }
    ((half8*)xh)[i] = o;
}

__global__ __launch_bounds__(256) void cast_w1_kernel(const float* __restrict__ W, _Float16* __restrict__ Wt) {
    int i = blockIdx.x * 256 + threadIdx.x;
    if (i >= HID * KP1) return;
    int n = i / KP1, k = i % KP1;
    float v = (k < IN_DIM) ? W[(size_t)k * HID + n] : 0.f;
    Wt[i] = (_Float16)v;
}

__global__ __launch_bounds__(256) void cast_wc_kernel(const float* __restrict__ W, _Float16* __restrict__ Wt) {
    int i = blockIdx.x * 256 + threadIdx.x;
    if (i >= LAYERS * HID * HID) return;
    int l = i / (HID * HID);
    int r = i % (HID * HID);
    int n = r / HID, k = r % HID;
    Wt[i] = (_Float16)W[(size_t)l * HID * HID + (size_t)k * HID + n];
}

// ---------------------------------------------------------------- fp16 MFMA GEMM
// headmajor=1 writes C as [head][node][32] (stride N_NODES rows per head slice)
__global__ __launch_bounds__(256) void gemm_mfma_kernel(const _Float16* __restrict__ A,
                                                        const _Float16* __restrict__ Wt,
                                                        const float* __restrict__ bias,
                                                        _Float16* __restrict__ C,
                                                        int M, int Kp, int addbias,
                                                        int headmajor) {
    __shared__ _Float16 As[128][32];
    __shared__ _Float16 Bs[128][32];
    const int tid = threadIdx.x;
    const int m0 = blockIdx.x * 128;
    const int n0 = blockIdx.y * 128;
    const int w = tid >> 6, lane = tid & 63;
    const int wm = (w & 1) * 64, wn = (w >> 1) * 64;
    const int quad = lane >> 4, m16 = lane & 15;

    f32x4 acc[4][4];
    #pragma unroll
    for (int i = 0; i < 4; i++)
        #pragma unroll
        for (int j = 0; j < 4; j++)
            acc[i][j] = (f32x4){0.f, 0.f, 0.f, 0.f};

    char* lA = (char*)&As[0][0] + w * 1024;   // wave-uniform LDS bases
    char* lB = (char*)&Bs[0][0] + w * 1024;

    for (int k0 = 0; k0 < Kp; k0 += 32) {
        #pragma unroll
        for (int i = 0; i < 2; i++) {
            int seg = tid + i * 256;
            int row = seg >> 2, off = seg & 3;
            GLDS16(&A[(size_t)(m0 + row) * Kp + k0 + off * 8], lA + i * 4096);
            GLDS16(&Wt[(size_t)(n0 + row) * Kp + k0 + off * 8], lB + i * 4096);
        }
        __syncthreads();

        half8 af[4], bf[4];
        #pragma unroll
        for (int i = 0; i < 4; i++) {
            af[i] = *(const half8*)&As[wm + i * 16 + m16][quad * 8];
            bf[i] = *(const half8*)&Bs[wn + i * 16 + m16][quad * 8];
        }
        #pragma unroll
        for (int mi = 0; mi < 4; mi++)
            #pragma unroll
            for (int ni = 0; ni < 4; ni++)
                acc[mi][ni] = __builtin_amdgcn_mfma_f32_16x16x32_f16(af[mi], bf[ni], acc[mi][ni], 0, 0, 0);
        __syncthreads();
    }

    #pragma unroll
    for (int mi = 0; mi < 4; mi++) {
        #pragma unroll
        for (int r = 0; r < 4; r++) {
            int row = m0 + wm + mi * 16 + quad * 4 + r;
            if (row < M) {
                #pragma unroll
                for (int ni = 0; ni < 4; ni++) {
                    int colg = n0 + wn + ni * 16 + m16;
                    float v = acc[mi][ni][r];
                    if (addbias) v += bias[colg];
                    if (headmajor) {
                        int hd = colg >> 5, oc = colg & 31;
                        C[((size_t)hd * N_NODES + row) * 32 + oc] = (_Float16)v;
                    } else {
                        C[(size_t)row * HID + colg] = (_Float16)v;
                    }
                }
            }
        }
    }
}

// ---------------------------------------------------------------- attention scores
// hw is head-major [head][node][32]; s arrays head-major [head][node].
// Wave = 8 nodes; lane = (node nd=lane>>3, head hd=lane&7).
__global__ __launch_bounds__(256) void score_kernel(const _Float16* __restrict__ hw,
                                                    const float* __restrict__ att_dst,
                                                    const float* __restrict__ att_src,
                                                    float* __restrict__ s_dst,
                                                    float* __restrict__ s_src) {
    int wv = threadIdx.x >> 6, lane = threadIdx.x & 63;
    int nd = lane >> 3, hd = lane & 7;
    float4 ad[8], as4[8];
    const float4* A4d = (const float4*)att_dst;
    const float4* A4s = (const float4*)att_src;
    #pragma unroll
    for (int j = 0; j < 8; j++) { ad[j] = A4d[hd * 8 + j]; as4[j] = A4s[hd * 8 + j]; }
    const half8* hw8 = (const half8*)hw;
    int nwaves = gridDim.x * 4;
    for (int g = blockIdx.x * 4 + wv; g < N_NODES / 8; g += nwaves) {
        int node = g * 8 + nd;
        float sd = 0.f, ss = 0.f;
        #pragma unroll
        for (int k = 0; k < 4; k++) {
            half8 v = hw8[((size_t)hd * N_NODES + node) * 4 + k];
            #pragma unroll
            for (int i = 0; i < 8; i++) {
                float f = (float)v[i];
                int q = k * 8 + i;
                sd += f * ((const float*)&ad[q >> 2])[q & 3];
                ss += f * ((const float*)&as4[q >> 2])[q & 3];
            }
        }
        s_dst[(size_t)hd * N_NODES + node] = sd;
        s_src[(size_t)hd * N_NODES + node] = ss;
    }
}

// ---------------------------------------------------------------- aggregation
// R13: L2-resident per-head window (head = blk&7 -> XCD) + LDS-staged 2-phase.
// Phase A (lane = slot, 64-wide): col + s_src gathers for 64 edges at once,
// exp ONCE per (edge,head), stage ex + (sn<<6) in wave-private LDS; per-lane
// dsum partial. Phase C (lane = 8 es x 8 cl): per group of 8 edges just
// {ds_read snb, ds_read ex, 8B hw gather, 4 fma}, depth-2 pipelined.
// Chunked at 128 edges -> any degree, no slow path.
__global__ __launch_bounds__(256, 8) void agg_kernel(const int* __restrict__ row_ptr,
                                                     const int* __restrict__ deg_arr,
                                                     const u16* __restrict__ col,
                                                     const float* __restrict__ s_dst,
                                                     const float* __restrict__ s_src,
                                                     const _Float16* __restrict__ hw,
                                                     const float* __restrict__ bias,
                                                     _Float16* __restrict__ h_out) {
    __shared__ float exL[4][128];
    __shared__ int   snL[4][128];

    const int wv   = threadIdx.x >> 6;
    const int lane = threadIdx.x & 63;
    const int head = blockIdx.x & (NB - 1);   // head == XCD
    const int ib   = blockIdx.x >> 3;         // 0..255 within head
    const int es   = lane >> 3;               // edge slot 0..7 (phase C)
    const int cl   = lane & 7;                // channel quad: 4 ch (8B)
    const int wid  = ib * 4 + wv;             // 0..1023
    const int NW   = (NAGG / NB) * 4;         // 1024 waves per head

    const float* sdh = s_dst + (size_t)head * N_NODES;
    const float* ssh = s_src + (size_t)head * N_NODES;
    const char*  hwb = (const char*)(hw + (size_t)head * N_NODES * 32) + cl * 8;

    const float* bpt = bias + head * 32 + cl * 4;
    float b0 = bpt[0], b1 = bpt[1], b2 = bpt[2], b3 = bpt[3];

    float* exw = &exL[wv][0];
    int*   snw = &snL[wv][0];

    for (int t = wid; t < N_NODES; t += NW) {
        int start = row_ptr[t];
        int pdeg  = row_ptr[t + 1] - start;   // multiple of 8, >= 8
        int deg   = deg_arr[t];
        float sdv = sdh[t];
        const u16* cb = col + start;

        float dsumL = 0.f;                    // phase-A lane partial
        float a0 = 0.f, a1 = 0.f, a2 = 0.f, a3 = 0.f;

        for (int c0 = 0; c0 < pdeg; c0 += 128) {
            int csz = min(pdeg - c0, 128);    // multiple of 8

            // ---------- phase A: 64-wide ex/snb staging ----------
            for (int b = 0; b < csz; b += 64) {
                int slot = b + lane;
                bool act = slot < csz;
                int sn = 0;
                if (act) sn = (int)cb[c0 + slot];
                float ss = ssh[(unsigned)sn];
                float a = sdv + ss;
                a = (a > 0.f) ? a : NEG_SLOPE * a;
                float ex = (act && (c0 + slot) < deg) ? __expf(a) : 0.f;
                if (act) { exw[slot] = ex; snw[slot] = sn << 6; }
                dsumL += ex;
            }

            // ---------- phase C: groups of 8, depth-2 pipeline ----------
            int ngrp = csz >> 3;              // 1..16
            int d0 = snw[es];
            int d1 = (ngrp > 1) ? snw[8 + es] : 0;
            half4v v0 = *(const half4v*)(hwb + (unsigned)d0);
            for (int g = 0; g < ngrp; g++) {
                int d2 = (g + 2 < ngrp) ? snw[(g + 2) * 8 + es] : 0;
                half4v vn = *(const half4v*)(hwb + (unsigned)d1);
                float e = exw[g * 8 + es];
                a0 += e * (float)v0[0];
                a1 += e * (float)v0[1];
                a2 += e * (float)v0[2];
                a3 += e * (float)v0[3];
                v0 = vn; d1 = d2;
            }
        }

        // dsum: full 64-lane reduce (phase-A layout spans all lanes)
        #pragma unroll
        for (int off = 1; off <= 32; off <<= 1) dsumL += __shfl_xor(dsumL, off);
        // acc: reduce over edge-slot bits (3,4,5)
        #pragma unroll
        for (int off = 8; off <= 32; off <<= 1) {
            a0 += __shfl_xor(a0, off);
            a1 += __shfl_xor(a1, off);
            a2 += __shfl_xor(a2, off);
            a3 += __shfl_xor(a3, off);
        }

        if (es == 0) {
            float inv = 1.f / (dsumL + 1e-16f);
            float o0 = a0 * inv + b0;
            float o1 = a1 * inv + b1;
            float o2 = a2 * inv + b2;
            float o3 = a3 * inv + b3;
            o0 = (o0 > 0.f) ? o0 : (__expf(o0) - 1.f);
            o1 = (o1 > 0.f) ? o1 : (__expf(o1) - 1.f);
            o2 = (o2 > 0.f) ? o2 : (__expf(o2) - 1.f);
            o3 = (o3 > 0.f) ? o3 : (__expf(o3) - 1.f);
            half4v ov;
            ov[0] = (_Float16)o0; ov[1] = (_Float16)o1;
            ov[2] = (_Float16)o2; ov[3] = (_Float16)o3;
            *(half4v*)(h_out + (size_t)t * HID + head * 32 + cl * 4) = ov;
        }
    }
}

// ---------------------------------------------------------------- head
__global__ __launch_bounds__(256) void head_kernel(const _Float16* __restrict__ h,
                                                   const int* __restrict__ target_mask,
                                                   const float* __restrict__ W,
                                                   const float* __restrict__ b,
                                                   float* __restrict__ out) {
    int s = blockIdx.x;
    int t = threadIdx.x;
    int n0 = target_mask[s * 2 + 0];
    int n1 = target_mask[s * 2 + 1];
    float f0 = (float)h[(size_t)n0 * HID + t];
    float f1 = (float)h[(size_t)n1 * HID + t];
    float a0 = f0 * W[t * 3 + 0] + f1 * W[(t + 256) * 3 + 0];
    float a1 = f0 * W[t * 3 + 1] + f1 * W[(t + 256) * 3 + 1];
    float a2 = f0 * W[t * 3 + 2] + f1 * W[(t + 256) * 3 + 2];
    #pragma unroll
    for (int off = 32; off >= 1; off >>= 1) {
        a0 += __shfl_xor(a0, off);
        a1 += __shfl_xor(a1, off);
        a2 += __shfl_xor(a2, off);
    }
    __shared__ float red[4][3];
    int wv = t >> 6, ln = t & 63;
    if (ln == 0) { red[wv][0] = a0; red[wv][1] = a1; red[wv][2] = a2; }
    __syncthreads();
    if (t < 3) {
        out[s * 3 + t] = red[0][t] + red[1][t] + red[2][t] + red[3][t] + b[t];
    }
}

// ---------------------------------------------------------------- launch

extern "C" void kernel_launch(void* const* d_in, const int* in_sizes, int n_in,
                              void* d_out, int out_size, void* d_ws, size_t ws_size,
                              hipStream_t stream) {
    const float* x        = (const float*)d_in[0];
    const int*   eidx     = (const int*)  d_in[1];
    const int*   tmask    = (const int*)  d_in[2];
    const float* lin1_W   = (const float*)d_in[3];
    const float* lin1_b   = (const float*)d_in[4];
    const float* convs_W  = (const float*)d_in[5];
    const float* att_dst  = (const float*)d_in[6];
    const float* att_src  = (const float*)d_in[7];
    const float* convs_b  = (const float*)d_in[8];
    const float* lin3_W   = (const float*)d_in[9];
    const float* lin3_b   = (const float*)d_in[10];
    float* out = (float*)d_out;

    char* ws = (char*)d_ws;
    size_t off = 0;
    auto alloc = [&](size_t bytes) -> void* {
        void* p = ws + off;
        off = (off + bytes + 255) & ~(size_t)255;
        return p;
    };
    _Float16* xh   = (_Float16*)alloc((size_t)N_PAD * KP1 * 2);
    _Float16* h    = (_Float16*)alloc((size_t)N_PAD * HID * 2);
    _Float16* hw   = (_Float16*)alloc((size_t)N_PAD * HID * 2);   // head-major [8][N][32]
    _Float16* w1t  = (_Float16*)alloc((size_t)HID * KP1 * 2);
    _Float16* wct  = (_Float16*)alloc((size_t)LAYERS * HID * HID * 2);
    float* sdst    = (float*)alloc((size_t)HEADS * N_NODES * 4);  // head-major
    float* ssrc    = (float*)alloc((size_t)HEADS * N_NODES * 4);  // head-major
    int*   counts  = (int*)  alloc((size_t)N_NODES * 4);
    int*   rowptr  = (int*)  alloc((size_t)(N_NODES + 1) * 4);
    int*   cursor  = (int*)  alloc((size_t)N_NODES * 4);
    u16*   col     = (u16*)  alloc((size_t)(EPAD + 32) * 2);
    ull*   bpart   = (ull*)  alloc((size_t)NB * BCAP * 8);
    int*   bcnt    = (int*)  alloc((size_t)NB * 4);
    int*   gcount  = (int*)  alloc((size_t)NBLK_P * NB * 4);
    int*   goff    = (int*)  alloc((size_t)NBLK_P * NB * 4);
    int*   bsum    = (int*)  alloc((size_t)NBLK_S * 4);
    int*   boff    = (int*)  alloc((size_t)NBLK_S * 4);

    const int* src = eidx;
    const int* tgt = eidx + E_EDGES;

    // CSR build
    hipMemsetAsync(counts, 0, (size_t)N_NODES * 4, stream);
    part_count_kernel<<<NBLK_P, 256, 0, stream>>>(tgt, gcount);
    part_scan_kernel<<<1, NBLK_P, 0, stream>>>(gcount, goff, bcnt);
    part_scatter_kernel<<<NBLK_P, 256, 0, stream>>>(src, tgt, goff, bpart);
    count_edges_kernel<<<NBLK_B, 256, 0, stream>>>(bpart, bcnt, counts);
    scan1_kernel<<<NBLK_S, 256, 0, stream>>>(counts, rowptr, bsum);
    scan2_kernel<<<1, 256, 0, stream>>>(bsum, boff, rowptr);
    scan3_kernel<<<NBLK_S, 256, 0, stream>>>(rowptr, boff, cursor);
    fill_edges_kernel<<<NBLK_B, 256, 0, stream>>>(bpart, bcnt, cursor, col);
    pad_edges_kernel<<<(N_NODES + 255) / 256, 256, 0, stream>>>(cursor, rowptr, col);

    // casts
    cast_x_kernel<<<(N_NODES * (KP1 / 8) + 255) / 256, 256, 0, stream>>>(x, xh);
    cast_w1_kernel<<<(HID * KP1 + 255) / 256, 256, 0, stream>>>(lin1_W, w1t);
    cast_wc_kernel<<<(LAYERS * HID * HID + 255) / 256, 256, 0, stream>>>(convs_W, wct);

    // lin1 (node-major output)
    gemm_mfma_kernel<<<dim3((N_NODES + 127) / 128, HID / 128), 256, 0, stream>>>(
        xh, w1t, lin1_b, h, N_NODES, KP1, 1, 0);

    for (int l = 0; l < LAYERS; l++) {
        // conv GEMM -> head-major hw
        gemm_mfma_kernel<<<dim3((N_NODES + 127) / 128, HID / 128), 256, 0, stream>>>(
            h, wct + (size_t)l * HID * HID, nullptr, hw, N_NODES, HID, 0, 1);
        score_kernel<<<256, 256, 0, stream>>>(
            hw, att_dst + (size_t)l * HEADS * OC, att_src + (size_t)l * HEADS * OC, sdst, ssrc);
        agg_kernel<<<NAGG, 256, 0, stream>>>(
            rowptr, counts, col, sdst, ssrc, hw, convs_b + (size_t)l * HID, h);
    }

    head_kernel<<<BSAMP, 256, 0, stream>>>(h, tmask, lin3_W, lin3_b, out);
}

// Round 6
// 1023.793 us; speedup vs baseline: 1.6955x; 1.0980x over previous
//
#include <hip/hip_runtime.h>
#include <math.h>

#define N_NODES 50000
#define N_PAD   50048            // padded rows for 128-row GEMM tiles
#define E_EDGES 1600000
#define ETOT    (E_EDGES + N_NODES)
#define EPAD    (E_EDGES + 8 * N_NODES)   // CSR rows padded to multiple of 8
#define IN_DIM  300
#define KP1     320              // IN_DIM padded to mult of 32
#define HID     256
#define HEADS   8
#define OC      32
#define LAYERS  4
#define BSAMP   1024
#define NEG_SLOPE 0.2f
#define NS1     (N_NODES + 1)    // s_src stride (sentinel slot at index N_NODES)

// XCD-bucketed CSR build
#define NB     8                 // buckets = XCDs (also heads in agg)
#define NPB    6250              // nodes per bucket (50000/8)
#define BCAP   262144            // per-bucket partition capacity (mean 206k)
#define NBLK_P 512               // partition blocks
#define NBLK_S 196               // scan blocks (50000/256 rounded up)
#define NBLK_B 2048              // bucket count/fill blocks (256 per bucket)
#define NAGG   2048              // agg blocks: head = blk&7 -> XCD-resident hw slice

typedef unsigned long long ull;
typedef unsigned short u16;
typedef _Float16 half8 __attribute__((ext_vector_type(8)));
typedef _Float16 half4v __attribute__((ext_vector_type(4)));
typedef float f32x4 __attribute__((ext_vector_type(4)));

#define GLDS16(g, l) __builtin_amdgcn_global_load_lds( \
    (const __attribute__((address_space(1))) void*)(g), \
    (__attribute__((address_space(3))) void*)(l), 16, 0, 0)

// ---------------------------------------------------------------- CSR build
// Two-pass block-local radix partition by tgt bucket. No global atomics.

__global__ __launch_bounds__(256) void part_count_kernel(const int* __restrict__ tgt,
                                                         int* __restrict__ gcount) {
    __shared__ int cnt[NB];
    if (threadIdx.x < NB) cnt[threadIdx.x] = 0;
    __syncthreads();
    const int chunk = (ETOT + NBLK_P - 1) / NBLK_P;
    int beg = blockIdx.x * chunk;
    int end = min(beg + chunk, ETOT);
    for (int e = beg + threadIdx.x; e < end; e += 256) {
        int t_ = (e < E_EDGES) ? tgt[e] : (e - E_EDGES);
        atomicAdd(&cnt[t_ / NPB], 1);
    }
    __syncthreads();
    if (threadIdx.x < NB) gcount[blockIdx.x * NB + threadIdx.x] = cnt[threadIdx.x];
}

// parallel scan over NBLK_P block-counts x NB buckets (1 block, 512 threads)
__global__ __launch_bounds__(512) void part_scan_kernel(const int* __restrict__ gcount,
                                                        int* __restrict__ goff,
                                                        int* __restrict__ bcnt) {
    __shared__ int arr[NBLK_P][NB];
    int k = threadIdx.x;
    int4 a = ((const int4*)gcount)[k * 2];
    int4 b = ((const int4*)gcount)[k * 2 + 1];
    int own[NB] = {a.x, a.y, a.z, a.w, b.x, b.y, b.z, b.w};
    #pragma unroll
    for (int j = 0; j < NB; j++) arr[k][j] = own[j];
    __syncthreads();
    for (int off = 1; off < NBLK_P; off <<= 1) {
        int tmp[NB];
        #pragma unroll
        for (int j = 0; j < NB; j++) tmp[j] = (k >= off) ? arr[k - off][j] : 0;
        __syncthreads();
        #pragma unroll
        for (int j = 0; j < NB; j++) arr[k][j] += tmp[j];
        __syncthreads();
    }
    int ex[NB];
    #pragma unroll
    for (int j = 0; j < NB; j++) ex[j] = arr[k][j] - own[j];   // exclusive
    ((int4*)goff)[k * 2]     = make_int4(ex[0], ex[1], ex[2], ex[3]);
    ((int4*)goff)[k * 2 + 1] = make_int4(ex[4], ex[5], ex[6], ex[7]);
    if (k == NBLK_P - 1) {
        #pragma unroll
        for (int j = 0; j < NB; j++) bcnt[j] = arr[k][j];
    }
}

__global__ __launch_bounds__(256) void part_scatter_kernel(const int* __restrict__ src,
                                                           const int* __restrict__ tgt,
                                                           const int* __restrict__ goff,
                                                           ull* __restrict__ bpart) {
    __shared__ int cur[NB];
    if (threadIdx.x < NB) cur[threadIdx.x] = goff[blockIdx.x * NB + threadIdx.x];
    __syncthreads();
    const int chunk = (ETOT + NBLK_P - 1) / NBLK_P;
    int beg = blockIdx.x * chunk;
    int end = min(beg + chunk, ETOT);
    for (int e = beg + threadIdx.x; e < end; e += 256) {
        int s_, t_;
        if (e < E_EDGES) { s_ = src[e]; t_ = tgt[e]; }
        else             { s_ = t_ = e - E_EDGES; }
        int b = t_ / NPB;
        int pos = atomicAdd(&cur[b], 1);
        bpart[(size_t)b * BCAP + pos] = ((ull)(unsigned)t_ << 32) | (unsigned)s_;
    }
}

// per-bucket degree count (blockIdx%8 = bucket -> XCD-local counts lines)
__global__ __launch_bounds__(256) void count_edges_kernel(const ull* __restrict__ bpart,
                                                          const int* __restrict__ bcnt,
                                                          int* counts) {
    int b = blockIdx.x & (NB - 1);
    int ib = blockIdx.x >> 3;
    int nblk = gridDim.x >> 3;
    int nb = bcnt[b];
    const ull* bp = bpart + (size_t)b * BCAP;
    for (int i = ib * 256 + threadIdx.x; i < nb; i += nblk * 256)
        atomicAdd(&counts[(int)(bp[i] >> 32)], 1);
}

// ---------------- parallel scan of padded counts (3 tiny kernels) ----------
__global__ __launch_bounds__(256) void scan1_kernel(const int* __restrict__ counts,
                                                    int* __restrict__ row_ptr,
                                                    int* __restrict__ bsum) {
    __shared__ int sums[256];
    int t = threadIdx.x;
    int i = blockIdx.x * 256 + t;
    int c = (i < N_NODES) ? ((counts[i] + 7) & ~7) : 0;
    sums[t] = c;
    __syncthreads();
    for (int off = 1; off < 256; off <<= 1) {
        int a = sums[t];
        int u = (t >= off) ? sums[t - off] : 0;
        __syncthreads();
        sums[t] = a + u;
        __syncthreads();
    }
    if (i < N_NODES) row_ptr[i] = sums[t] - c;   // local exclusive
    if (t == 255) bsum[blockIdx.x] = sums[255];
}

__global__ __launch_bounds__(256) void scan2_kernel(const int* __restrict__ bsum,
                                                    int* __restrict__ boff,
                                                    int* __restrict__ row_ptr) {
    __shared__ int sums[256];
    int t = threadIdx.x;
    int b = (t < NBLK_S) ? bsum[t] : 0;
    sums[t] = b;
    __syncthreads();
    for (int off = 1; off < 256; off <<= 1) {
        int a = sums[t];
        int u = (t >= off) ? sums[t - off] : 0;
        __syncthreads();
        sums[t] = a + u;
        __syncthreads();
    }
    if (t < NBLK_S) boff[t] = sums[t] - b;
    if (t == 255) row_ptr[N_NODES] = sums[255];
}

__global__ __launch_bounds__(256) void scan3_kernel(int* __restrict__ row_ptr,
                                                    const int* __restrict__ boff,
                                                    int* __restrict__ cursor) {
    int i = blockIdx.x * 256 + threadIdx.x;
    if (i >= N_NODES) return;
    int v = row_ptr[i] + boff[blockIdx.x];
    row_ptr[i] = v;
    cursor[i]  = v;
}

// per-bucket scatter into col (cursor + col lines XCD-local); col is u16
__global__ __launch_bounds__(256) void fill_edges_kernel(const ull* __restrict__ bpart,
                                                         const int* __restrict__ bcnt,
                                                         int* cursor, u16* __restrict__ col) {
    int b = blockIdx.x & (NB - 1);
    int ib = blockIdx.x >> 3;
    int nblk = gridDim.x >> 3;
    int nb = bcnt[b];
    const ull* bp = bpart + (size_t)b * BCAP;
    for (int i = ib * 256 + threadIdx.x; i < nb; i += nblk * 256) {
        ull pk = bp[i];
        int t_ = (int)(pk >> 32);
        int s_ = (int)pk;
        int pos = atomicAdd(&cursor[t_], 1);
        col[pos] = (u16)s_;
    }
}

// fill pad slots with SENTINEL node id (s_src[sentinel] = -1e30 -> ex == 0)
__global__ __launch_bounds__(256) void pad_edges_kernel(const int* __restrict__ cursor,
                                                        const int* __restrict__ row_ptr,
                                                        u16* __restrict__ col) {
    int i = blockIdx.x * 256 + threadIdx.x;
    if (i >= N_NODES) return;
    int e = cursor[i];            // true end after fill
    int pe = row_ptr[i + 1];      // padded end
    for (; e < pe; e++) col[e] = (u16)N_NODES;
}

// ---------------------------------------------------------------- fp32 -> fp16 casts

__global__ __launch_bounds__(256) void cast_x_kernel(const float* __restrict__ x, _Float16* __restrict__ xh) {
    int i = blockIdx.x * 256 + threadIdx.x;          // over 50000*40 half8s
    if (i >= N_NODES * (KP1 / 8)) return;
    int r = i / (KP1 / 8), c8 = i % (KP1 / 8);
    half8 o;
    const float4* xr = (const float4*)(x + (size_t)r * IN_DIM);
    if (c8 < 37) {
        float4 u = xr[c8 * 2], v = xr[c8 * 2 + 1];
        o[0] = (_Float16)u.x; o[1] = (_Float16)u.y; o[2] = (_Float16)u.z; o[3] = (_Float16)u.w;
        o[4] = (_Float16)v.x; o[5] = (_Float16)v.y; o[6] = (_Float16)v.z; o[7] = (_Float16)v.w;
    } else if (c8 == 37) {
        float4 u = xr[74];
        o[0] = (_Float16)u.x; o[1] = (_Float16)u.y; o[2] = (_Float16)u.z; o[3] = (_Float16)u.w;
        o[4] = o[5] = o[6] = o[7] = (_Float16)0.f;
    } else {
        #pragma unroll
        for (int j = 0; j < 8; j++) o[j] = (_Float16)0.f;
    }
    ((half8*)xh)[i] = o;
}

__global__ __launch_bounds__(256) void cast_w1_kernel(const float* __restrict__ W, _Float16* __restrict__ Wt) {
    int i = blockIdx.x * 256 + threadIdx.x;
    if (i >= HID * KP1) return;
    int n = i / KP1, k = i % KP1;
    float v = (k < IN_DIM) ? W[(size_t)k * HID + n] : 0.f;
    Wt[i] = (_Float16)v;
}

__global__ __launch_bounds__(256) void cast_wc_kernel(const float* __restrict__ W, _Float16* __restrict__ Wt) {
    int i = blockIdx.x * 256 + threadIdx.x;
    if (i >= LAYERS * HID * HID) return;
    int l = i / (HID * HID);
    int r = i % (HID * HID);
    int n = r / HID, k = r % HID;
    Wt[i] = (_Float16)W[(size_t)l * HID * HID + (size_t)k * HID + n];
}

// ---------------------------------------------------------------- fp16 MFMA GEMM
// headmajor=1 writes C as [head][node][32] (stride N_NODES rows per head slice)
__global__ __launch_bounds__(256) void gemm_mfma_kernel(const _Float16* __restrict__ A,
                                                        const _Float16* __restrict__ Wt,
                                                        const float* __restrict__ bias,
                                                        _Float16* __restrict__ C,
                                                        int M, int Kp, int addbias,
                                                        int headmajor) {
    __shared__ _Float16 As[128][32];
    __shared__ _Float16 Bs[128][32];
    const int tid = threadIdx.x;
    const int m0 = blockIdx.x * 128;
    const int n0 = blockIdx.y * 128;
    const int w = tid >> 6, lane = tid & 63;
    const int wm = (w & 1) * 64, wn = (w >> 1) * 64;
    const int quad = lane >> 4, m16 = lane & 15;

    f32x4 acc[4][4];
    #pragma unroll
    for (int i = 0; i < 4; i++)
        #pragma unroll
        for (int j = 0; j < 4; j++)
            acc[i][j] = (f32x4){0.f, 0.f, 0.f, 0.f};

    char* lA = (char*)&As[0][0] + w * 1024;   // wave-uniform LDS bases
    char* lB = (char*)&Bs[0][0] + w * 1024;

    for (int k0 = 0; k0 < Kp; k0 += 32) {
        #pragma unroll
        for (int i = 0; i < 2; i++) {
            int seg = tid + i * 256;
            int row = seg >> 2, off = seg & 3;
            GLDS16(&A[(size_t)(m0 + row) * Kp + k0 + off * 8], lA + i * 4096);
            GLDS16(&Wt[(size_t)(n0 + row) * Kp + k0 + off * 8], lB + i * 4096);
        }
        __syncthreads();

        half8 af[4], bf[4];
        #pragma unroll
        for (int i = 0; i < 4; i++) {
            af[i] = *(const half8*)&As[wm + i * 16 + m16][quad * 8];
            bf[i] = *(const half8*)&Bs[wn + i * 16 + m16][quad * 8];
        }
        #pragma unroll
        for (int mi = 0; mi < 4; mi++)
            #pragma unroll
            for (int ni = 0; ni < 4; ni++)
                acc[mi][ni] = __builtin_amdgcn_mfma_f32_16x16x32_f16(af[mi], bf[ni], acc[mi][ni], 0, 0, 0);
        __syncthreads();
    }

    #pragma unroll
    for (int mi = 0; mi < 4; mi++) {
        #pragma unroll
        for (int r = 0; r < 4; r++) {
            int row = m0 + wm + mi * 16 + quad * 4 + r;
            if (row < M) {
                #pragma unroll
                for (int ni = 0; ni < 4; ni++) {
                    int colg = n0 + wn + ni * 16 + m16;
                    float v = acc[mi][ni][r];
                    if (addbias) v += bias[colg];
                    if (headmajor) {
                        int hd = colg >> 5, oc = colg & 31;
                        C[((size_t)hd * N_NODES + row) * 32 + oc] = (_Float16)v;
                    } else {
                        C[(size_t)row * HID + colg] = (_Float16)v;
                    }
                }
            }
        }
    }
}

// ---------------------------------------------------------------- attention scores
// hw is head-major [head][node][32]; s_dst [head][node]; s_src [head][N+1]
// (slot N is the sentinel = -1e30 so padded edges contribute ex = 0).
__global__ __launch_bounds__(256) void score_kernel(const _Float16* __restrict__ hw,
                                                    const float* __restrict__ att_dst,
                                                    const float* __restrict__ att_src,
                                                    float* __restrict__ s_dst,
                                                    float* __restrict__ s_src) {
    if (blockIdx.x == 0 && threadIdx.x < HEADS)
        s_src[(size_t)threadIdx.x * NS1 + N_NODES] = -1e30f;
    int wv = threadIdx.x >> 6, lane = threadIdx.x & 63;
    int nd = lane >> 3, hd = lane & 7;
    float4 ad[8], as4[8];
    const float4* A4d = (const float4*)att_dst;
    const float4* A4s = (const float4*)att_src;
    #pragma unroll
    for (int j = 0; j < 8; j++) { ad[j] = A4d[hd * 8 + j]; as4[j] = A4s[hd * 8 + j]; }
    const half8* hw8 = (const half8*)hw;
    int nwaves = gridDim.x * 4;
    for (int g = blockIdx.x * 4 + wv; g < N_NODES / 8; g += nwaves) {
        int node = g * 8 + nd;
        float sd = 0.f, ss = 0.f;
        #pragma unroll
        for (int k = 0; k < 4; k++) {
            half8 v = hw8[((size_t)hd * N_NODES + node) * 4 + k];
            #pragma unroll
            for (int i = 0; i < 8; i++) {
                float f = (float)v[i];
                int q = k * 8 + i;
                sd += f * ((const float*)&ad[q >> 2])[q & 3];
                ss += f * ((const float*)&as4[q >> 2])[q & 3];
            }
        }
        s_dst[(size_t)hd * N_NODES + node] = sd;
        s_src[(size_t)hd * NS1 + node] = ss;
    }
}

// ---------------------------------------------------------------- aggregation
// R14: R13 structure (head = blk&7 -> XCD L2 window, 2-phase LDS staging) with
// a minimum instruction stream: sentinel pads (no deg masks), saddr gathers
// (scalar bases + 32-bit voffsets), leaky = fmax(a,.2a), dsum folded into
// phase C's 3-round reduce, and a NODE-PAIR per wave (two independent gather
// chains; split epilogue: es==0 lanes store node0, es==1 store node1).
__global__ __launch_bounds__(256, 8) void agg_kernel(const int* __restrict__ row_ptr,
                                                     const u16* __restrict__ col,
                                                     const float* __restrict__ s_dst,
                                                     const float* __restrict__ s_src,
                                                     const _Float16* __restrict__ hw,
                                                     const float* __restrict__ bias,
                                                     _Float16* __restrict__ h_out) {
    __shared__ float exL[4][2][128];
    __shared__ int   snL[4][2][128];

    const int wv   = threadIdx.x >> 6;
    const int lane = threadIdx.x & 63;
    const int head = blockIdx.x & (NB - 1);   // head == XCD
    const int ib   = blockIdx.x >> 3;         // 0..255 within head
    const int es   = lane >> 3;               // edge slot 0..7 (phase C)
    const int cl   = lane & 7;                // channel quad: 4 ch (8B)
    const int wid  = ib * 4 + wv;             // 0..1023
    const int NW   = (NAGG / NB) * 4;         // 1024 waves per head

    const float* sdh = s_dst + (size_t)head * N_NODES;
    const float* ssh = s_src + (size_t)head * NS1;          // scalar base
    const char*  hwh = (const char*)(hw + (size_t)head * N_NODES * 32);
    const unsigned vcl = (unsigned)(cl * 8);  // per-lane byte offset in row

    const float* bpt = bias + head * 32 + cl * 4;
    float b0 = bpt[0], b1 = bpt[1], b2 = bpt[2], b3 = bpt[3];

    // phase A staging lambda: stage [0,pdeg) of node region s
    auto stageA = [&](int s, int start, int pdeg, float sdv) {
        float* exw = &exL[wv][s][0];
        int*   snw = &snL[wv][s][0];
        for (int b = 0; b < pdeg; b += 64) {
            int slot = b + lane;
            if (slot < pdeg) {
                int sn = (int)col[start + slot];
                float ss = ssh[(unsigned)sn];
                float a = sdv + ss;
                a = fmaxf(a, NEG_SLOPE * a);
                exw[slot] = __expf(a);        // sentinel -> exp(-2e29) == 0
                snw[slot] = sn << 6;
            }
        }
    };

    // phase C lambda: accumulate node region s over pdeg edges
    auto phaseC = [&](int s, int pdeg, float& dsum,
                      float& a0, float& a1, float& a2, float& a3) {
        float* exw = &exL[wv][s][0];
        int*   snw = &snL[wv][s][0];
        int ngrp = pdeg >> 3;                 // multiple of 8, >= 8
        int d0 = snw[es];
        int d1 = (ngrp > 1) ? snw[8 + es] : d0;
        half4v v0 = *(const half4v*)(hwh + ((unsigned)d0 | vcl));
        for (int g = 0; g < ngrp; g++) {
            int d2 = (g + 2 < ngrp) ? snw[(g + 2) * 8 + es] : 0;
            half4v vn = *(const half4v*)(hwh + ((unsigned)d1 | vcl));
            float e = exw[g * 8 + es];
            dsum += e;
            a0 += e * (float)v0[0];
            a1 += e * (float)v0[1];
            a2 += e * (float)v0[2];
            a3 += e * (float)v0[3];
            v0 = vn; d1 = d2;
        }
    };

    for (int tb = wid * 2; tb < N_NODES; tb += NW * 2) {
        int t0 = tb, t1 = tb + 1;             // tb even < 50000 -> t1 valid
        int r0 = row_ptr[t0];
        int r1 = row_ptr[t1];
        int r2 = row_ptr[t1 + 1];
        int pd0 = r1 - r0, pd1 = r2 - r1;
        float sdv0 = sdh[t0], sdv1 = sdh[t1];

        float ds0 = 0.f, ds1 = 0.f;
        float x0 = 0.f, x1 = 0.f, x2 = 0.f, x3 = 0.f;
        float y0 = 0.f, y1 = 0.f, y2 = 0.f, y3 = 0.f;

        if (pd0 <= 128 && pd1 <= 128) {
            // fast pair path: both phase A's issued back-to-back
            stageA(0, r0, pd0, sdv0);
            stageA(1, r1, pd1, sdv1);
            phaseC(0, pd0, ds0, x0, x1, x2, x3);
            phaseC(1, pd1, ds1, y0, y1, y2, y3);
        } else {
            // rare chunked path (pdeg > 128), per node
            for (int c0 = 0; c0 < pd0; c0 += 128) {
                int csz = min(pd0 - c0, 128);
                stageA(0, r0 + c0, csz, sdv0);
                phaseC(0, csz, ds0, x0, x1, x2, x3);
            }
            for (int c0 = 0; c0 < pd1; c0 += 128) {
                int csz = min(pd1 - c0, 128);
                stageA(1, r1 + c0, csz, sdv1);
                phaseC(1, csz, ds1, y0, y1, y2, y3);
            }
        }

        // fused reduce over edge-slot bits (3,4,5): 10 values
        #pragma unroll
        for (int off = 8; off <= 32; off <<= 1) {
            ds0 += __shfl_xor(ds0, off);
            ds1 += __shfl_xor(ds1, off);
            x0 += __shfl_xor(x0, off);
            x1 += __shfl_xor(x1, off);
            x2 += __shfl_xor(x2, off);
            x3 += __shfl_xor(x3, off);
            y0 += __shfl_xor(y0, off);
            y1 += __shfl_xor(y1, off);
            y2 += __shfl_xor(y2, off);
            y3 += __shfl_xor(y3, off);
        }

        // split epilogue: es==0 lanes own node0, es==1 lanes own node1
        if (es < 2) {
            float ds = (es == 0) ? ds0 : ds1;
            float s0 = (es == 0) ? x0 : y0;
            float s1 = (es == 0) ? x1 : y1;
            float s2 = (es == 0) ? x2 : y2;
            float s3 = (es == 0) ? x3 : y3;
            float inv = 1.f / (ds + 1e-16f);
            float o0 = s0 * inv + b0;
            float o1 = s1 * inv + b1;
            float o2 = s2 * inv + b2;
            float o3 = s3 * inv + b3;
            o0 = (o0 > 0.f) ? o0 : (__expf(o0) - 1.f);
            o1 = (o1 > 0.f) ? o1 : (__expf(o1) - 1.f);
            o2 = (o2 > 0.f) ? o2 : (__expf(o2) - 1.f);
            o3 = (o3 > 0.f) ? o3 : (__expf(o3) - 1.f);
            half4v ov;
            ov[0] = (_Float16)o0; ov[1] = (_Float16)o1;
            ov[2] = (_Float16)o2; ov[3] = (_Float16)o3;
            // t = tb + es
            *(half4v*)(h_out + (size_t)(tb + es) * HID + head * 32 + cl * 4) = ov;
        }
    }
}

// ---------------------------------------------------------------- head
__global__ __launch_bounds__(256) void head_kernel(const _Float16* __restrict__ h,
                                                   const int* __restrict__ target_mask,
                                                   const float* __restrict__ W,
                                                   const float* __restrict__ b,
                                                   float* __restrict__ out) {
    int s = blockIdx.x;
    int t = threadIdx.x;
    int n0 = target_mask[s * 2 + 0];
    int n1 = target_mask[s * 2 + 1];
    float f0 = (float)h[(size_t)n0 * HID + t];
    float f1 = (float)h[(size_t)n1 * HID + t];
    float a0 = f0 * W[t * 3 + 0] + f1 * W[(t + 256) * 3 + 0];
    float a1 = f0 * W[t * 3 + 1] + f1 * W[(t + 256) * 3 + 1];
    float a2 = f0 * W[t * 3 + 2] + f1 * W[(t + 256) * 3 + 2];
    #pragma unroll
    for (int off = 32; off >= 1; off >>= 1) {
        a0 += __shfl_xor(a0, off);
        a1 += __shfl_xor(a1, off);
        a2 += __shfl_xor(a2, off);
    }
    __shared__ float red[4][3];
    int wv = t >> 6, ln = t & 63;
    if (ln == 0) { red[wv][0] = a0; red[wv][1] = a1; red[wv][2] = a2; }
    __syncthreads();
    if (t < 3) {
        out[s * 3 + t] = red[0][t] + red[1][t] + red[2][t] + red[3][t] + b[t];
    }
}

// ---------------------------------------------------------------- launch

extern "C" void kernel_launch(void* const* d_in, const int* in_sizes, int n_in,
                              void* d_out, int out_size, void* d_ws, size_t ws_size,
                              hipStream_t stream) {
    const float* x        = (const float*)d_in[0];
    const int*   eidx     = (const int*)  d_in[1];
    const int*   tmask    = (const int*)  d_in[2];
    const float* lin1_W   = (const float*)d_in[3];
    const float* lin1_b   = (const float*)d_in[4];
    const float* convs_W  = (const float*)d_in[5];
    const float* att_dst  = (const float*)d_in[6];
    const float* att_src  = (const float*)d_in[7];
    const float* convs_b  = (const float*)d_in[8];
    const float* lin3_W   = (const float*)d_in[9];
    const float* lin3_b   = (const float*)d_in[10];
    float* out = (float*)d_out;

    char* ws = (char*)d_ws;
    size_t off = 0;
    auto alloc = [&](size_t bytes) -> void* {
        void* p = ws + off;
        off = (off + bytes + 255) & ~(size_t)255;
        return p;
    };
    _Float16* xh   = (_Float16*)alloc((size_t)N_PAD * KP1 * 2);
    _Float16* h    = (_Float16*)alloc((size_t)N_PAD * HID * 2);
    _Float16* hw   = (_Float16*)alloc((size_t)N_PAD * HID * 2);   // head-major [8][N][32]
    _Float16* w1t  = (_Float16*)alloc((size_t)HID * KP1 * 2);
    _Float16* wct  = (_Float16*)alloc((size_t)LAYERS * HID * HID * 2);
    float* sdst    = (float*)alloc((size_t)HEADS * N_NODES * 4);  // head-major
    float* ssrc    = (float*)alloc((size_t)HEADS * NS1 * 4);      // head-major + sentinel
    int*   counts  = (int*)  alloc((size_t)N_NODES * 4);
    int*   rowptr  = (int*)  alloc((size_t)(N_NODES + 1) * 4);
    int*   cursor  = (int*)  alloc((size_t)N_NODES * 4);
    u16*   col     = (u16*)  alloc((size_t)(EPAD + 32) * 2);
    ull*   bpart   = (ull*)  alloc((size_t)NB * BCAP * 8);
    int*   bcnt    = (int*)  alloc((size_t)NB * 4);
    int*   gcount  = (int*)  alloc((size_t)NBLK_P * NB * 4);
    int*   goff    = (int*)  alloc((size_t)NBLK_P * NB * 4);
    int*   bsum    = (int*)  alloc((size_t)NBLK_S * 4);
    int*   boff    = (int*)  alloc((size_t)NBLK_S * 4);

    const int* src = eidx;
    const int* tgt = eidx + E_EDGES;

    // CSR build
    hipMemsetAsync(counts, 0, (size_t)N_NODES * 4, stream);
    part_count_kernel<<<NBLK_P, 256, 0, stream>>>(tgt, gcount);
    part_scan_kernel<<<1, NBLK_P, 0, stream>>>(gcount, goff, bcnt);
    part_scatter_kernel<<<NBLK_P, 256, 0, stream>>>(src, tgt, goff, bpart);
    count_edges_kernel<<<NBLK_B, 256, 0, stream>>>(bpart, bcnt, counts);
    scan1_kernel<<<NBLK_S, 256, 0, stream>>>(counts, rowptr, bsum);
    scan2_kernel<<<1, 256, 0, stream>>>(bsum, boff, rowptr);
    scan3_kernel<<<NBLK_S, 256, 0, stream>>>(rowptr, boff, cursor);
    fill_edges_kernel<<<NBLK_B, 256, 0, stream>>>(bpart, bcnt, cursor, col);
    pad_edges_kernel<<<(N_NODES + 255) / 256, 256, 0, stream>>>(cursor, rowptr, col);

    // casts
    cast_x_kernel<<<(N_NODES * (KP1 / 8) + 255) / 256, 256, 0, stream>>>(x, xh);
    cast_w1_kernel<<<(HID * KP1 + 255) / 256, 256, 0, stream>>>(lin1_W, w1t);
    cast_wc_kernel<<<(LAYERS * HID * HID + 255) / 256, 256, 0, stream>>>(convs_W, wct);

    // lin1 (node-major output)
    gemm_mfma_kernel<<<dim3((N_NODES + 127) / 128, HID / 128), 256, 0, stream>>>(
        xh, w1t, lin1_b, h, N_NODES, KP1, 1, 0);

    for (int l = 0; l < LAYERS; l++) {
        // conv GEMM -> head-major hw
        gemm_mfma_kernel<<<dim3((N_NODES + 127) / 128, HID / 128), 256, 0, stream>>>(
            h, wct + (size_t)l * HID * HID, nullptr, hw, N_NODES, HID, 0, 1);
        score_kernel<<<256, 256, 0, stream>>>(
            hw, att_dst + (size_t)l * HEADS * OC, att_src + (size_t)l * HEADS * OC, sdst, ssrc);
        agg_kernel<<<NAGG, 256, 0, stream>>>(
            rowptr, col, sdst, ssrc, hw, convs_b + (size_t)l * HID, h);
    }

    head_kernel<<<BSAMP, 256, 0, stream>>>(h, tmask, lin3_W, lin3_b, out);
}

// Round 7
// 988.910 us; speedup vs baseline: 1.7553x; 1.0353x over previous
//
#include <hip/hip_runtime.h>
#include <math.h>

#define N_NODES 50000
#define N_PAD   50048            // padded rows for 128-row GEMM tiles
#define E_EDGES 1600000
#define ETOT    (E_EDGES + N_NODES)
#define EPAD    (E_EDGES + 8 * N_NODES)   // CSR rows padded to multiple of 8
#define IN_DIM  300
#define KP1     320              // IN_DIM padded to mult of 32
#define HID     256
#define HEADS   8
#define OC      32
#define LAYERS  4
#define BSAMP   1024
#define NEG_SLOPE 0.2f
#define NS1     (N_NODES + 1)    // s_src stride (sentinel slot at index N_NODES)

// XCD-bucketed CSR build
#define NB     8                 // buckets = XCDs (also heads in agg)
#define NPB    6250              // nodes per bucket (50000/8)
#define BCAP   262144            // per-bucket partition capacity (mean 206k)
#define NBLK_P 512               // partition blocks
#define NBLK_S 196               // scan blocks (50000/256 rounded up)
#define NBLK_B 2048              // bucket count/fill blocks (256 per bucket)
#define NAGG   2048              // agg blocks: head = blk&7 -> XCD-resident hw slice

typedef unsigned long long ull;
typedef unsigned short u16;
typedef _Float16 half8 __attribute__((ext_vector_type(8)));
typedef _Float16 half4v __attribute__((ext_vector_type(4)));
typedef float f32x4 __attribute__((ext_vector_type(4)));

#define GLDS16(g, l) __builtin_amdgcn_global_load_lds( \
    (const __attribute__((address_space(1))) void*)(g), \
    (__attribute__((address_space(3))) void*)(l), 16, 0, 0)

// ---------------------------------------------------------------- CSR build
// Two-pass block-local radix partition by tgt bucket. No global atomics.

__global__ __launch_bounds__(256) void part_count_kernel(const int* __restrict__ tgt,
                                                         int* __restrict__ gcount) {
    __shared__ int cnt[NB];
    if (threadIdx.x < NB) cnt[threadIdx.x] = 0;
    __syncthreads();
    const int chunk = (ETOT + NBLK_P - 1) / NBLK_P;
    int beg = blockIdx.x * chunk;
    int end = min(beg + chunk, ETOT);
    for (int e = beg + threadIdx.x; e < end; e += 256) {
        int t_ = (e < E_EDGES) ? tgt[e] : (e - E_EDGES);
        atomicAdd(&cnt[t_ / NPB], 1);
    }
    __syncthreads();
    if (threadIdx.x < NB) gcount[blockIdx.x * NB + threadIdx.x] = cnt[threadIdx.x];
}

// parallel scan over NBLK_P block-counts x NB buckets (1 block, 512 threads)
__global__ __launch_bounds__(512) void part_scan_kernel(const int* __restrict__ gcount,
                                                        int* __restrict__ goff,
                                                        int* __restrict__ bcnt) {
    __shared__ int arr[NBLK_P][NB];
    int k = threadIdx.x;
    int4 a = ((const int4*)gcount)[k * 2];
    int4 b = ((const int4*)gcount)[k * 2 + 1];
    int own[NB] = {a.x, a.y, a.z, a.w, b.x, b.y, b.z, b.w};
    #pragma unroll
    for (int j = 0; j < NB; j++) arr[k][j] = own[j];
    __syncthreads();
    for (int off = 1; off < NBLK_P; off <<= 1) {
        int tmp[NB];
        #pragma unroll
        for (int j = 0; j < NB; j++) tmp[j] = (k >= off) ? arr[k - off][j] : 0;
        __syncthreads();
        #pragma unroll
        for (int j = 0; j < NB; j++) arr[k][j] += tmp[j];
        __syncthreads();
    }
    int ex[NB];
    #pragma unroll
    for (int j = 0; j < NB; j++) ex[j] = arr[k][j] - own[j];   // exclusive
    ((int4*)goff)[k * 2]     = make_int4(ex[0], ex[1], ex[2], ex[3]);
    ((int4*)goff)[k * 2 + 1] = make_int4(ex[4], ex[5], ex[6], ex[7]);
    if (k == NBLK_P - 1) {
        #pragma unroll
        for (int j = 0; j < NB; j++) bcnt[j] = arr[k][j];
    }
}

__global__ __launch_bounds__(256) void part_scatter_kernel(const int* __restrict__ src,
                                                           const int* __restrict__ tgt,
                                                           const int* __restrict__ goff,
                                                           ull* __restrict__ bpart) {
    __shared__ int cur[NB];
    if (threadIdx.x < NB) cur[threadIdx.x] = goff[blockIdx.x * NB + threadIdx.x];
    __syncthreads();
    const int chunk = (ETOT + NBLK_P - 1) / NBLK_P;
    int beg = blockIdx.x * chunk;
    int end = min(beg + chunk, ETOT);
    for (int e = beg + threadIdx.x; e < end; e += 256) {
        int s_, t_;
        if (e < E_EDGES) { s_ = src[e]; t_ = tgt[e]; }
        else             { s_ = t_ = e - E_EDGES; }
        int b = t_ / NPB;
        int pos = atomicAdd(&cur[b], 1);
        bpart[(size_t)b * BCAP + pos] = ((ull)(unsigned)t_ << 32) | (unsigned)s_;
    }
}

// per-bucket degree count (blockIdx%8 = bucket -> XCD-local counts lines)
__global__ __launch_bounds__(256) void count_edges_kernel(const ull* __restrict__ bpart,
                                                          const int* __restrict__ bcnt,
                                                          int* counts) {
    int b = blockIdx.x & (NB - 1);
    int ib = blockIdx.x >> 3;
    int nblk = gridDim.x >> 3;
    int nb = bcnt[b];
    const ull* bp = bpart + (size_t)b * BCAP;
    for (int i = ib * 256 + threadIdx.x; i < nb; i += nblk * 256)
        atomicAdd(&counts[(int)(bp[i] >> 32)], 1);
}

// ---------------- parallel scan of padded counts (3 tiny kernels) ----------
__global__ __launch_bounds__(256) void scan1_kernel(const int* __restrict__ counts,
                                                    int* __restrict__ row_ptr,
                                                    int* __restrict__ bsum) {
    __shared__ int sums[256];
    int t = threadIdx.x;
    int i = blockIdx.x * 256 + t;
    int c = (i < N_NODES) ? ((counts[i] + 7) & ~7) : 0;
    sums[t] = c;
    __syncthreads();
    for (int off = 1; off < 256; off <<= 1) {
        int a = sums[t];
        int u = (t >= off) ? sums[t - off] : 0;
        __syncthreads();
        sums[t] = a + u;
        __syncthreads();
    }
    if (i < N_NODES) row_ptr[i] = sums[t] - c;   // local exclusive
    if (t == 255) bsum[blockIdx.x] = sums[255];
}

__global__ __launch_bounds__(256) void scan2_kernel(const int* __restrict__ bsum,
                                                    int* __restrict__ boff,
                                                    int* __restrict__ row_ptr) {
    __shared__ int sums[256];
    int t = threadIdx.x;
    int b = (t < NBLK_S) ? bsum[t] : 0;
    sums[t] = b;
    __syncthreads();
    for (int off = 1; off < 256; off <<= 1) {
        int a = sums[t];
        int u = (t >= off) ? sums[t - off] : 0;
        __syncthreads();
        sums[t] = a + u;
        __syncthreads();
    }
    if (t < NBLK_S) boff[t] = sums[t] - b;
    if (t == 255) row_ptr[N_NODES] = sums[255];
}

__global__ __launch_bounds__(256) void scan3_kernel(int* __restrict__ row_ptr,
                                                    const int* __restrict__ boff,
                                                    int* __restrict__ cursor) {
    int i = blockIdx.x * 256 + threadIdx.x;
    if (i >= N_NODES) return;
    int v = row_ptr[i] + boff[blockIdx.x];
    row_ptr[i] = v;
    cursor[i]  = v;
}

// per-bucket scatter into col (cursor + col lines XCD-local); col is u16
__global__ __launch_bounds__(256) void fill_edges_kernel(const ull* __restrict__ bpart,
                                                         const int* __restrict__ bcnt,
                                                         int* cursor, u16* __restrict__ col) {
    int b = blockIdx.x & (NB - 1);
    int ib = blockIdx.x >> 3;
    int nblk = gridDim.x >> 3;
    int nb = bcnt[b];
    const ull* bp = bpart + (size_t)b * BCAP;
    for (int i = ib * 256 + threadIdx.x; i < nb; i += nblk * 256) {
        ull pk = bp[i];
        int t_ = (int)(pk >> 32);
        int s_ = (int)pk;
        int pos = atomicAdd(&cursor[t_], 1);
        col[pos] = (u16)s_;
    }
}

// fill pad slots with SENTINEL node id (s_src[sentinel] = -1e30 -> ex == 0)
__global__ __launch_bounds__(256) void pad_edges_kernel(const int* __restrict__ cursor,
                                                        const int* __restrict__ row_ptr,
                                                        u16* __restrict__ col) {
    int i = blockIdx.x * 256 + threadIdx.x;
    if (i >= N_NODES) return;
    int e = cursor[i];            // true end after fill
    int pe = row_ptr[i + 1];      // padded end
    for (; e < pe; e++) col[e] = (u16)N_NODES;
}

// ---------------------------------------------------------------- fp32 -> fp16 casts

__global__ __launch_bounds__(256) void cast_x_kernel(const float* __restrict__ x, _Float16* __restrict__ xh) {
    int i = blockIdx.x * 256 + threadIdx.x;          // over 50000*40 half8s
    if (i >= N_NODES * (KP1 / 8)) return;
    int r = i / (KP1 / 8), c8 = i % (KP1 / 8);
    half8 o;
    const float4* xr = (const float4*)(x + (size_t)r * IN_DIM);
    if (c8 < 37) {
        float4 u = xr[c8 * 2], v = xr[c8 * 2 + 1];
        o[0] = (_Float16)u.x; o[1] = (_Float16)u.y; o[2] = (_Float16)u.z; o[3] = (_Float16)u.w;
        o[4] = (_Float16)v.x; o[5] = (_Float16)v.y; o[6] = (_Float16)v.z; o[7] = (_Float16)v.w;
    } else if (c8 == 37) {
        float4 u = xr[74];
        o[0] = (_Float16)u.x; o[1] = (_Float16)u.y; o[2] = (_Float16)u.z; o[3] = (_Float16)u.w;
        o[4] = o[5] = o[6] = o[7] = (_Float16)0.f;
    } else {
        #pragma unroll
        for (int j = 0; j < 8; j++) o[j] = (_Float16)0.f;
    }
    ((half8*)xh)[i] = o;
}

__global__ __launch_bounds__(256) void cast_w1_kernel(const float* __restrict__ W, _Float16* __restrict__ Wt) {
    int i = blockIdx.x * 256 + threadIdx.x;
    if (i >= HID * KP1) return;
    int n = i / KP1, k = i % KP1;
    float v = (k < IN_DIM) ? W[(size_t)k * HID + n] : 0.f;
    Wt[i] = (_Float16)v;
}

__global__ __launch_bounds__(256) void cast_wc_kernel(const float* __restrict__ W, _Float16* __restrict__ Wt) {
    int i = blockIdx.x * 256 + threadIdx.x;
    if (i >= LAYERS * HID * HID) return;
    int l = i / (HID * HID);
    int r = i % (HID * HID);
    int n = r / HID, k = r % HID;
    Wt[i] = (_Float16)W[(size_t)l * HID * HID + (size_t)k * HID + n];
}

// ---------------------------------------------------------------- fp16 MFMA GEMM
// headmajor=1 writes C as [head][node][32] (stride N_NODES rows per head slice)
__global__ __launch_bounds__(256) void gemm_mfma_kernel(const _Float16* __restrict__ A,
                                                        const _Float16* __restrict__ Wt,
                                                        const float* __restrict__ bias,
                                                        _Float16* __restrict__ C,
                                                        int M, int Kp, int addbias,
                                                        int headmajor) {
    __shared__ _Float16 As[128][32];
    __shared__ _Float16 Bs[128][32];
    const int tid = threadIdx.x;
    const int m0 = blockIdx.x * 128;
    const int n0 = blockIdx.y * 128;
    const int w = tid >> 6, lane = tid & 63;
    const int wm = (w & 1) * 64, wn = (w >> 1) * 64;
    const int quad = lane >> 4, m16 = lane & 15;

    f32x4 acc[4][4];
    #pragma unroll
    for (int i = 0; i < 4; i++)
        #pragma unroll
        for (int j = 0; j < 4; j++)
            acc[i][j] = (f32x4){0.f, 0.f, 0.f, 0.f};

    char* lA = (char*)&As[0][0] + w * 1024;   // wave-uniform LDS bases
    char* lB = (char*)&Bs[0][0] + w * 1024;

    for (int k0 = 0; k0 < Kp; k0 += 32) {
        #pragma unroll
        for (int i = 0; i < 2; i++) {
            int seg = tid + i * 256;
            int row = seg >> 2, off = seg & 3;
            GLDS16(&A[(size_t)(m0 + row) * Kp + k0 + off * 8], lA + i * 4096);
            GLDS16(&Wt[(size_t)(n0 + row) * Kp + k0 + off * 8], lB + i * 4096);
        }
        __syncthreads();

        half8 af[4], bf[4];
        #pragma unroll
        for (int i = 0; i < 4; i++) {
            af[i] = *(const half8*)&As[wm + i * 16 + m16][quad * 8];
            bf[i] = *(const half8*)&Bs[wn + i * 16 + m16][quad * 8];
        }
        #pragma unroll
        for (int mi = 0; mi < 4; mi++)
            #pragma unroll
            for (int ni = 0; ni < 4; ni++)
                acc[mi][ni] = __builtin_amdgcn_mfma_f32_16x16x32_f16(af[mi], bf[ni], acc[mi][ni], 0, 0, 0);
        __syncthreads();
    }

    #pragma unroll
    for (int mi = 0; mi < 4; mi++) {
        #pragma unroll
        for (int r = 0; r < 4; r++) {
            int row = m0 + wm + mi * 16 + quad * 4 + r;
            if (row < M) {
                #pragma unroll
                for (int ni = 0; ni < 4; ni++) {
                    int colg = n0 + wn + ni * 16 + m16;
                    float v = acc[mi][ni][r];
                    if (addbias) v += bias[colg];
                    if (headmajor) {
                        int hd = colg >> 5, oc = colg & 31;
                        C[((size_t)hd * N_NODES + row) * 32 + oc] = (_Float16)v;
                    } else {
                        C[(size_t)row * HID + colg] = (_Float16)v;
                    }
                }
            }
        }
    }
}

// ---------------------------------------------------------------- attention scores
// hw is head-major [head][node][32]; s_dst [head][node]; s_src [head][N+1]
// (slot N is the sentinel = -1e30 so padded edges contribute ex = 0).
__global__ __launch_bounds__(256) void score_kernel(const _Float16* __restrict__ hw,
                                                    const float* __restrict__ att_dst,
                                                    const float* __restrict__ att_src,
                                                    float* __restrict__ s_dst,
                                                    float* __restrict__ s_src) {
    if (blockIdx.x == 0 && threadIdx.x < HEADS)
        s_src[(size_t)threadIdx.x * NS1 + N_NODES] = -1e30f;
    int wv = threadIdx.x >> 6, lane = threadIdx.x & 63;
    int nd = lane >> 3, hd = lane & 7;
    float4 ad[8], as4[8];
    const float4* A4d = (const float4*)att_dst;
    const float4* A4s = (const float4*)att_src;
    #pragma unroll
    for (int j = 0; j < 8; j++) { ad[j] = A4d[hd * 8 + j]; as4[j] = A4s[hd * 8 + j]; }
    const half8* hw8 = (const half8*)hw;
    int nwaves = gridDim.x * 4;
    for (int g = blockIdx.x * 4 + wv; g < N_NODES / 8; g += nwaves) {
        int node = g * 8 + nd;
        float sd = 0.f, ss = 0.f;
        #pragma unroll
        for (int k = 0; k < 4; k++) {
            half8 v = hw8[((size_t)hd * N_NODES + node) * 4 + k];
            #pragma unroll
            for (int i = 0; i < 8; i++) {
                float f = (float)v[i];
                int q = k * 8 + i;
                sd += f * ((const float*)&ad[q >> 2])[q & 3];
                ss += f * ((const float*)&as4[q >> 2])[q & 3];
            }
        }
        s_dst[(size_t)hd * N_NODES + node] = sd;
        s_src[(size_t)hd * NS1 + node] = ss;
    }
}

// ---------------------------------------------------------------- aggregation
// R15: head = blk&7 -> XCD L2 window + node-split wave halves.
// Lane = nh (node half, bit 5) x es (8 edge slots, bits 2-4) x cl (4 channel
// lanes x 16B, bits 0-1). Phase A: sentinel pads, exp once per edge, staged
// to LDS. Phase C: both nodes' edge streams run in the SAME instruction
// stream (lanes 0-31 node0, 32-63 node1) -> 16 edge-heads per ~14 inst.
// Shorter region zero-padded (sn=0 -> row-0 gather x ex=0, harmless).
// Reduce: 3 rounds (es bits only). One epilogue issue covers both nodes.
__global__ __launch_bounds__(256, 8) void agg_kernel(const int* __restrict__ row_ptr,
                                                     const u16* __restrict__ col,
                                                     const float* __restrict__ s_dst,
                                                     const float* __restrict__ s_src,
                                                     const _Float16* __restrict__ hw,
                                                     const float* __restrict__ bias,
                                                     _Float16* __restrict__ h_out) {
    __shared__ float exL[4][2][128];
    __shared__ int   snL[4][2][128];

    const int wv   = threadIdx.x >> 6;
    const int lane = threadIdx.x & 63;
    const int head = blockIdx.x & (NB - 1);   // head == XCD
    const int ib   = blockIdx.x >> 3;         // 0..255 within head
    const int nh   = lane >> 5;               // node half
    const int es   = (lane >> 2) & 7;         // edge slot 0..7
    const int cl   = lane & 3;                // channel lane: 8 ch (16B)
    const int wid  = ib * 4 + wv;             // 0..1023
    const int NW   = (NAGG / NB) * 4;         // 1024 waves per head

    const float* sdh = s_dst + (size_t)head * N_NODES;
    const float* ssh = s_src + (size_t)head * NS1;          // scalar base
    const char*  hwh = (const char*)(hw + (size_t)head * N_NODES * 32);
    const unsigned vcl = (unsigned)(cl * 16); // per-lane byte offset in 64B row

    float bb[8];
    {
        const float* bpt = bias + head * 32 + cl * 8;
        #pragma unroll
        for (int i = 0; i < 8; i++) bb[i] = bpt[i];
    }

    float* exw = &exL[wv][nh][0];   // phase-C per-lane region
    int*   snw = &snL[wv][nh][0];

    // stage csz slots of col[startg..] into region s (exp once per edge)
    auto stage = [&](int s, int startg, int csz, float sdv) {
        float* exd = &exL[wv][s][0];
        int*   snd = &snL[wv][s][0];
        for (int b = 0; b < csz; b += 64) {
            int slot = b + lane;
            if (slot < csz) {
                int sn = (int)col[startg + slot];
                float a = sdv + ssh[(unsigned)sn];
                a = fmaxf(a, NEG_SLOPE * a);
                exd[slot] = __expf(a);        // sentinel -> 0
                snd[slot] = sn << 6;
            }
        }
    };

    float dsum, a0, a1, a2, a3, a4, a5, a6, a7;

    // accumulate ngrp groups from this lane's region (both halves in lockstep)
    auto phaseC = [&](int ngrp) {
        int d0 = snw[es];
        int d1 = (ngrp > 1) ? snw[8 + es] : 0;
        half8 v0 = *(const half8*)(hwh + ((unsigned)d0 | vcl));
        for (int g = 0; g < ngrp; g++) {
            int d2 = (g + 2 < ngrp) ? snw[(g + 2) * 8 + es] : 0;
            half8 vn = *(const half8*)(hwh + ((unsigned)d1 | vcl));
            float e = exw[g * 8 + es];
            dsum += e;
            a0 += e * (float)v0[0];
            a1 += e * (float)v0[1];
            a2 += e * (float)v0[2];
            a3 += e * (float)v0[3];
            a4 += e * (float)v0[4];
            a5 += e * (float)v0[5];
            a6 += e * (float)v0[6];
            a7 += e * (float)v0[7];
            v0 = vn; d1 = d2;
        }
    };

    for (int tb = wid * 2; tb < N_NODES; tb += NW * 2) {
        int r0 = row_ptr[tb];
        int r1 = row_ptr[tb + 1];
        int r2 = row_ptr[tb + 2];
        int pd0 = r1 - r0, pd1 = r2 - r1;     // multiples of 8, >= 8
        float sdv0 = sdh[tb], sdv1 = sdh[tb + 1];

        dsum = 0.f;
        a0 = a1 = a2 = a3 = a4 = a5 = a6 = a7 = 0.f;

        if (pd0 <= 128 && pd1 <= 128) {
            int mx = max(pd0, pd1);
            stage(0, r0, pd0, sdv0);
            stage(1, r1, pd1, sdv1);
            // zero-pad shorter region up to mx
            for (int slot = pd0 + lane; slot < mx; slot += 64) {
                exL[wv][0][slot] = 0.f; snL[wv][0][slot] = 0;
            }
            for (int slot = pd1 + lane; slot < mx; slot += 64) {
                exL[wv][1][slot] = 0.f; snL[wv][1][slot] = 0;
            }
            phaseC(mx >> 3);
        } else {
            // rare chunked path (pdeg > 128): one node at a time,
            // other region zeroed so its half accumulates 0.
            #pragma unroll 1
            for (int s = 0; s < 2; s++) {
                for (int slot = lane; slot < 128; slot += 64) {
                    exL[wv][s ^ 1][slot] = 0.f; snL[wv][s ^ 1][slot] = 0;
                }
                int rs = s ? r1 : r0;
                int pds = s ? pd1 : pd0;
                float sdvs = s ? sdv1 : sdv0;
                for (int c0 = 0; c0 < pds; c0 += 128) {
                    int csz = min(pds - c0, 128);
                    stage(s, rs + c0, csz, sdvs);
                    phaseC(csz >> 3);
                }
            }
        }

        // reduce over edge-slot bits (2,3,4) — node halves never mix
        #pragma unroll
        for (int off = 4; off <= 16; off <<= 1) {
            dsum += __shfl_xor(dsum, off);
            a0 += __shfl_xor(a0, off);
            a1 += __shfl_xor(a1, off);
            a2 += __shfl_xor(a2, off);
            a3 += __shfl_xor(a3, off);
            a4 += __shfl_xor(a4, off);
            a5 += __shfl_xor(a5, off);
            a6 += __shfl_xor(a6, off);
            a7 += __shfl_xor(a7, off);
        }

        // epilogue: es==0 lanes (nh*32 + cl) store their node's 8 channels
        if (es == 0) {
            float inv = 1.f / (dsum + 1e-16f);
            float o[8] = {a0 * inv + bb[0], a1 * inv + bb[1],
                          a2 * inv + bb[2], a3 * inv + bb[3],
                          a4 * inv + bb[4], a5 * inv + bb[5],
                          a6 * inv + bb[6], a7 * inv + bb[7]};
            half8 ov;
            #pragma unroll
            for (int i = 0; i < 8; i++) {
                float v = (o[i] > 0.f) ? o[i] : (__expf(o[i]) - 1.f);
                ov[i] = (_Float16)v;
            }
            *(half8*)(h_out + (size_t)(tb + nh) * HID + head * 32 + cl * 8) = ov;
        }
    }
}

// ---------------------------------------------------------------- head
__global__ __launch_bounds__(256) void head_kernel(const _Float16* __restrict__ h,
                                                   const int* __restrict__ target_mask,
                                                   const float* __restrict__ W,
                                                   const float* __restrict__ b,
                                                   float* __restrict__ out) {
    int s = blockIdx.x;
    int t = threadIdx.x;
    int n0 = target_mask[s * 2 + 0];
    int n1 = target_mask[s * 2 + 1];
    float f0 = (float)h[(size_t)n0 * HID + t];
    float f1 = (float)h[(size_t)n1 * HID + t];
    float a0 = f0 * W[t * 3 + 0] + f1 * W[(t + 256) * 3 + 0];
    float a1 = f0 * W[t * 3 + 1] + f1 * W[(t + 256) * 3 + 1];
    float a2 = f0 * W[t * 3 + 2] + f1 * W[(t + 256) * 3 + 2];
    #pragma unroll
    for (int off = 32; off >= 1; off >>= 1) {
        a0 += __shfl_xor(a0, off);
        a1 += __shfl_xor(a1, off);
        a2 += __shfl_xor(a2, off);
    }
    __shared__ float red[4][3];
    int wv = t >> 6, ln = t & 63;
    if (ln == 0) { red[wv][0] = a0; red[wv][1] = a1; red[wv][2] = a2; }
    __syncthreads();
    if (t < 3) {
        out[s * 3 + t] = red[0][t] + red[1][t] + red[2][t] + red[3][t] + b[t];
    }
}

// ---------------------------------------------------------------- launch

extern "C" void kernel_launch(void* const* d_in, const int* in_sizes, int n_in,
                              void* d_out, int out_size, void* d_ws, size_t ws_size,
                              hipStream_t stream) {
    const float* x        = (const float*)d_in[0];
    const int*   eidx     = (const int*)  d_in[1];
    const int*   tmask    = (const int*)  d_in[2];
    const float* lin1_W   = (const float*)d_in[3];
    const float* lin1_b   = (const float*)d_in[4];
    const float* convs_W  = (const float*)d_in[5];
    const float* att_dst  = (const float*)d_in[6];
    const float* att_src  = (const float*)d_in[7];
    const float* convs_b  = (const float*)d_in[8];
    const float* lin3_W   = (const float*)d_in[9];
    const float* lin3_b   = (const float*)d_in[10];
    float* out = (float*)d_out;

    char* ws = (char*)d_ws;
    size_t off = 0;
    auto alloc = [&](size_t bytes) -> void* {
        void* p = ws + off;
        off = (off + bytes + 255) & ~(size_t)255;
        return p;
    };
    _Float16* xh   = (_Float16*)alloc((size_t)N_PAD * KP1 * 2);
    _Float16* h    = (_Float16*)alloc((size_t)N_PAD * HID * 2);
    _Float16* hw   = (_Float16*)alloc((size_t)N_PAD * HID * 2);   // head-major [8][N][32]
    _Float16* w1t  = (_Float16*)alloc((size_t)HID * KP1 * 2);
    _Float16* wct  = (_Float16*)alloc((size_t)LAYERS * HID * HID * 2);
    float* sdst    = (float*)alloc((size_t)HEADS * N_NODES * 4);  // head-major
    float* ssrc    = (float*)alloc((size_t)HEADS * NS1 * 4);      // head-major + sentinel
    int*   counts  = (int*)  alloc((size_t)N_NODES * 4);
    int*   rowptr  = (int*)  alloc((size_t)(N_NODES + 1) * 4);
    int*   cursor  = (int*)  alloc((size_t)N_NODES * 4);
    u16*   col     = (u16*)  alloc((size_t)(EPAD + 32) * 2);
    ull*   bpart   = (ull*)  alloc((size_t)NB * BCAP * 8);
    int*   bcnt    = (int*)  alloc((size_t)NB * 4);
    int*   gcount  = (int*)  alloc((size_t)NBLK_P * NB * 4);
    int*   goff    = (int*)  alloc((size_t)NBLK_P * NB * 4);
    int*   bsum    = (int*)  alloc((size_t)NBLK_S * 4);
    int*   boff    = (int*)  alloc((size_t)NBLK_S * 4);

    const int* src = eidx;
    const int* tgt = eidx + E_EDGES;

    // CSR build
    hipMemsetAsync(counts, 0, (size_t)N_NODES * 4, stream);
    part_count_kernel<<<NBLK_P, 256, 0, stream>>>(tgt, gcount);
    part_scan_kernel<<<1, NBLK_P, 0, stream>>>(gcount, goff, bcnt);
    part_scatter_kernel<<<NBLK_P, 256, 0, stream>>>(src, tgt, goff, bpart);
    count_edges_kernel<<<NBLK_B, 256, 0, stream>>>(bpart, bcnt, counts);
    scan1_kernel<<<NBLK_S, 256, 0, stream>>>(counts, rowptr, bsum);
    scan2_kernel<<<1, 256, 0, stream>>>(bsum, boff, rowptr);
    scan3_kernel<<<NBLK_S, 256, 0, stream>>>(rowptr, boff, cursor);
    fill_edges_kernel<<<NBLK_B, 256, 0, stream>>>(bpart, bcnt, cursor, col);
    pad_edges_kernel<<<(N_NODES + 255) / 256, 256, 0, stream>>>(cursor, rowptr, col);

    // casts
    cast_x_kernel<<<(N_NODES * (KP1 / 8) + 255) / 256, 256, 0, stream>>>(x, xh);
    cast_w1_kernel<<<(HID * KP1 + 255) / 256, 256, 0, stream>>>(lin1_W, w1t);
    cast_wc_kernel<<<(LAYERS * HID * HID + 255) / 256, 256, 0, stream>>>(convs_W, wct);

    // lin1 (node-major output)
    gemm_mfma_kernel<<<dim3((N_NODES + 127) / 128, HID / 128), 256, 0, stream>>>(
        xh, w1t, lin1_b, h, N_NODES, KP1, 1, 0);

    for (int l = 0; l < LAYERS; l++) {
        // conv GEMM -> head-major hw
        gemm_mfma_kernel<<<dim3((N_NODES + 127) / 128, HID / 128), 256, 0, stream>>>(
            h, wct + (size_t)l * HID * HID, nullptr, hw, N_NODES, HID, 0, 1);
        score_kernel<<<512, 256, 0, stream>>>(
            hw, att_dst + (size_t)l * HEADS * OC, att_src + (size_t)l * HEADS * OC, sdst, ssrc);
        agg_kernel<<<NAGG, 256, 0, stream>>>(
            rowptr, col, sdst, ssrc, hw, convs_b + (size_t)l * HID, h);
    }

    head_kernel<<<BSAMP, 256, 0, stream>>>(h, tmask, lin3_W, lin3_b, out);
}